// Round 8
// baseline (169.146 us; speedup 1.0000x reference)
//
#include <hip/hip_runtime.h>
#include <hip/hip_bf16.h>
#include <stdint.h>

// ---------- types / helpers ----------
typedef __attribute__((ext_vector_type(8))) short s8v;      // 8 x bf16 (4 VGPR)
typedef __attribute__((ext_vector_type(4))) float f32x4;
typedef __attribute__((ext_vector_type(16))) float f32x16;

union V16 { uint4 u4; unsigned int u[4]; s8v s; };

__device__ inline s8v u4_to_s8(uint4 v) { V16 c; c.u4 = v; return c.s; }
__device__ inline s8v words_to_s8(unsigned int a, unsigned int b, unsigned int c, unsigned int d) {
  V16 t; t.u[0] = a; t.u[1] = b; t.u[2] = c; t.u[3] = d; return t.s;
}
__device__ inline unsigned short f2b(float f) {
  __hip_bfloat16 h = __float2bfloat16(f);
  unsigned short u; __builtin_memcpy(&u, &h, 2); return u;
}
__device__ inline unsigned int pack2(float lo, float hi) {
  return ((unsigned int)f2b(hi) << 16) | (unsigned int)f2b(lo);
}
// packed f32->bf16 pair (RNE), 1 instruction
__device__ inline unsigned int cvtpk(float lo, float hi) {
  unsigned int r; asm("v_cvt_pk_bf16_f32 %0, %1, %2" : "=v"(r) : "v"(lo), "v"(hi)); return r;
}
__device__ inline float exp2_fast(float x) {
#if __has_builtin(__builtin_amdgcn_exp2f)
  return __builtin_amdgcn_exp2f(x);
#else
  float y; asm("v_exp_f32 %0, %1" : "=v"(y) : "v"(x)); return y;
#endif
}
// async global->LDS, 16B per lane; LDS dest = wave-uniform base + lane*16
__device__ inline void gld16(const void* g, void* lds) {
  __builtin_amdgcn_global_load_lds((const __attribute__((address_space(1))) void*)g,
                                   (__attribute__((address_space(3))) void*)lds, 16, 0, 0);
}

#define LOG2E 1.4426950408889634f

// ---------- fused convert kernel (x, wq, wk, wv, wo, rpe_table) ----------
__global__ void cvt_fused_kernel(const float* __restrict__ x, const float* __restrict__ wq,
                                 const float* __restrict__ wk, const float* __restrict__ wv,
                                 const float* __restrict__ wo, const float* __restrict__ tb,
                                 __hip_bfloat16* __restrict__ XB, __hip_bfloat16* __restrict__ WQKV,
                                 __hip_bfloat16* __restrict__ WOb, __hip_bfloat16* __restrict__ TBL) {
  const int bid = blockIdx.x;
  if (bid < 4096) {
    size_t i = ((size_t)bid * 256 + threadIdx.x) * 8;
    const float* src; __hip_bfloat16* dst; size_t off;
    if (i < 4194304)      { src = x;  dst = XB;             off = i; }
    else if (i < 5242880) { src = wq; dst = WQKV;           off = i - 4194304; }
    else if (i < 6291456) { src = wk; dst = WQKV + 1048576; off = i - 5242880; }
    else if (i < 7340032) { src = wv; dst = WQKV + 2097152; off = i - 6291456; }
    else                  { src = wo; dst = WOb;            off = i - 7340032; }
    const float4* s4 = (const float4*)(src + off);
    float4 a = s4[0], b = s4[1];
    uint4 o;
    o.x = pack2(a.x, a.y); o.y = pack2(a.z, a.w);
    o.z = pack2(b.x, b.y); o.w = pack2(b.z, b.w);
    *(uint4*)(dst + off) = o;
  } else {
    // rpe_table [16][9999][64] f32 -> TBL [16][2048][64] bf16, pre-scaled by log2e (row 2047 zero)
    size_t i = ((size_t)(bid - 4096) * 256 + threadIdx.x) * 8;
    int h = (int)(i >> 17);
    int rem = (int)(i & 131071);
    int r = rem >> 6, c = rem & 63;
    uint4 o;
    if (r < 2047) {
      const float4* s4 = (const float4*)(tb + ((size_t)h * 9999 + r) * 64 + c);
      float4 a = s4[0], b = s4[1];
      o.x = pack2(a.x * LOG2E, a.y * LOG2E); o.y = pack2(a.z * LOG2E, a.w * LOG2E);
      o.z = pack2(b.x * LOG2E, b.y * LOG2E); o.w = pack2(b.z * LOG2E, b.w * LOG2E);
    } else { o.x = 0u; o.y = 0u; o.z = 0u; o.w = 0u; }
    *(uint4*)(TBL + i) = o;
  }
}

// ---------- QKV GEMM: C[m][n] = XB[m]·WQKV[n] + bias, n-class -> Q / K(scaled) / VT ----------
__global__ __launch_bounds__(256, 3) void gemm_qkv(
    const __hip_bfloat16* __restrict__ A,      // XB [4096][1024]
    const __hip_bfloat16* __restrict__ Bt,     // WQKV [3072][1024]
    const float* __restrict__ bq, const float* __restrict__ bk, const float* __restrict__ bv,
    __hip_bfloat16* __restrict__ QB, __hip_bfloat16* __restrict__ KB,
    __hip_bfloat16* __restrict__ VTB) {
  __shared__ __align__(16) char smem[32768];
  char* As = smem;
  char* Bs = smem + 16384;
  const int tid = threadIdx.x;
  const int w = tid >> 6, l = tid & 63;
  const int wr = w >> 1, wc = w & 1;
  const int lr = l & 15, lg = l >> 4;
  const int m0 = blockIdx.y * 128, n0 = blockIdx.x * 128;

  f32x4 acc[4][4] = {};

  for (int kt = 0; kt < 16; ++kt) {
    __syncthreads();
    #pragma unroll
    for (int i = 0; i < 4; ++i) {
      const int off = i * 4096 + w * 1024;
      const int loff = off + l * 16;
      const int row = loff >> 7;
      const int cb = loff & 127;
      const int sc = cb ^ ((row & 7) << 4);
      gld16((const char*)A  + (size_t)(m0 + row) * 2048 + kt * 128 + sc, As + off);
      gld16((const char*)Bt + (size_t)(n0 + row) * 2048 + kt * 128 + sc, Bs + off);
    }
    asm volatile("s_waitcnt vmcnt(0)" ::: "memory");
    __syncthreads();
    #pragma unroll
    for (int ks = 0; ks < 2; ++ks) {
      uint4 af[4], bf4[4];
      #pragma unroll
      for (int i = 0; i < 4; ++i) {
        const int ra = wr * 64 + i * 16 + lr;
        const int rb = wc * 64 + i * 16 + lr;
        const int cb = ks * 64 + lg * 16;
        af[i]  = *(const uint4*)(As + ra * 128 + (cb ^ ((ra & 7) << 4)));
        bf4[i] = *(const uint4*)(Bs + rb * 128 + (cb ^ ((rb & 7) << 4)));
      }
      #pragma unroll
      for (int i = 0; i < 4; ++i) {
        #pragma unroll
        for (int j = 0; j < 4; ++j)
          acc[i][j] = __builtin_amdgcn_mfma_f32_16x16x32_bf16(u4_to_s8(af[i]), u4_to_s8(bf4[j]), acc[i][j], 0, 0, 0);
      }
    }
  }

  const int mrow = m0 + wr * 64 + lg * 4;
  const int ncol = n0 + wc * 64 + lr;
  const int cls = blockIdx.x >> 3;            // 0 = Q, 1 = K, 2 = V (block-uniform)

  if (cls < 2) {
    const float sc = cls ? 0.125f * LOG2E : 1.0f;
    const float* bias = cls ? bk : bq;
    __hip_bfloat16* op = cls ? KB : QB;
    #pragma unroll
    for (int j = 0; j < 4; ++j) {
      const int n = ncol - cls * 1024 + j * 16;
      const float bia = bias[n];
      const int hh = n >> 6, hd = n & 63;
      #pragma unroll
      for (int i = 0; i < 4; ++i) {
        #pragma unroll
        for (int r = 0; r < 4; ++r) {
          const int m = mrow + i * 16 + r;
          const int bb = m >> 10, ss = m & 1023;
          op[(((size_t)(bb * 16 + hh)) * 1024 + ss) * 64 + hd] = __float2bfloat16((acc[i][j][r] + bia) * sc);
        }
      }
    }
  } else {
    // V: write VT [B][H][64][S]; quad of consecutive s -> one 8B store
    #pragma unroll
    for (int j = 0; j < 4; ++j) {
      const int f = ncol - 2048 + j * 16;      // v feature = h*64+hd
      const float bia = bv[f];
      const int fh = f >> 6, fd = f & 63;
      #pragma unroll
      for (int i = 0; i < 4; ++i) {
        const int m = mrow + i * 16;          // quad m..m+3, m%4==0
        const int bb = m >> 10, ss = m & 1023;
        ushort4 qv;
        qv.x = f2b(acc[i][j][0] + bia); qv.y = f2b(acc[i][j][1] + bia);
        qv.z = f2b(acc[i][j][2] + bia); qv.w = f2b(acc[i][j][3] + bia);
        *(ushort4*)((char*)VTB + (((size_t)bb * 1048576 + (size_t)fh * 65536 + fd * 1024 + ss) * 2)) = qv;
      }
    }
  }
}

// ---------- out-proj GEMM: d_out[m][n] = CTX[m]·WOb[n] + bo, f32 out ----------
__global__ __launch_bounds__(256, 3) void gemm_out(
    const __hip_bfloat16* __restrict__ A,      // CTX [4096][1024]
    const __hip_bfloat16* __restrict__ Bt,     // WOb [1024][1024]
    const float* __restrict__ bo,
    float* __restrict__ out) {
  __shared__ __align__(16) char smem[32768];
  char* As = smem;
  char* Bs = smem + 16384;
  const int tid = threadIdx.x;
  const int w = tid >> 6, l = tid & 63;
  const int wr = w >> 1, wc = w & 1;
  const int lr = l & 15, lg = l >> 4;
  const int m0 = blockIdx.y * 128, n0 = blockIdx.x * 128;

  f32x4 acc[4][4] = {};

  for (int kt = 0; kt < 16; ++kt) {
    __syncthreads();
    #pragma unroll
    for (int i = 0; i < 4; ++i) {
      const int off = i * 4096 + w * 1024;
      const int loff = off + l * 16;
      const int row = loff >> 7;
      const int cb = loff & 127;
      const int sc = cb ^ ((row & 7) << 4);
      gld16((const char*)A  + (size_t)(m0 + row) * 2048 + kt * 128 + sc, As + off);
      gld16((const char*)Bt + (size_t)(n0 + row) * 2048 + kt * 128 + sc, Bs + off);
    }
    asm volatile("s_waitcnt vmcnt(0)" ::: "memory");
    __syncthreads();
    #pragma unroll
    for (int ks = 0; ks < 2; ++ks) {
      uint4 af[4], bf4[4];
      #pragma unroll
      for (int i = 0; i < 4; ++i) {
        const int ra = wr * 64 + i * 16 + lr;
        const int rb = wc * 64 + i * 16 + lr;
        const int cb = ks * 64 + lg * 16;
        af[i]  = *(const uint4*)(As + ra * 128 + (cb ^ ((ra & 7) << 4)));
        bf4[i] = *(const uint4*)(Bs + rb * 128 + (cb ^ ((rb & 7) << 4)));
      }
      #pragma unroll
      for (int i = 0; i < 4; ++i) {
        #pragma unroll
        for (int j = 0; j < 4; ++j)
          acc[i][j] = __builtin_amdgcn_mfma_f32_16x16x32_bf16(u4_to_s8(af[i]), u4_to_s8(bf4[j]), acc[i][j], 0, 0, 0);
      }
    }
  }

  const int mrow = m0 + wr * 64 + lg * 4;
  const int ncol = n0 + wc * 64 + lr;
  #pragma unroll
  for (int j = 0; j < 4; ++j) {
    const int n = ncol + j * 16;
    const float bia = bo[n];
    #pragma unroll
    for (int i = 0; i < 4; ++i) {
      #pragma unroll
      for (int r = 0; r < 4; ++r) {
        const int m = mrow + i * 16 + r;
        out[(size_t)m * 1024 + n] = acc[i][j][r] + bia;
      }
    }
  }
}

// ---------- fused attention with RPE (v8: 8-wave k-split, NO staging, barrier-free loop) ----------
// grid 512 (XCD-chunk swizzled), 512 threads = 8 waves. Waves 0-3 (group 0) process even kt,
// waves 4-7 (group 1) odd kt, same 128 q-rows (wave pair (w, w+4) owns q0=qb+32w).
// All K/T/V MFMA fragments are loaded DIRECTLY from global (L2-resident after XCD swizzle;
// addresses byte-identical to what the old LDS round-trip delivered). LDS holds ONLY the
// per-wave f32 rel scratch (r6-verbatim geometry) -> the k-loop has ZERO block barriers;
// waves free-run. 64 KB LDS + launch_bounds(512,2) -> 2 blocks/CU = 16 waves/CU (4/SIMD),
// 2x the waves of r6 -- attacks the measured ~50% latency idle.
// rel wrap-store (r5/r6-verified): order t2,t0,t1; pos4 masks t2:&124, t0:(&252)|128, t1:&252.
// Final merge (2 syncthreads): odd group writes cacc/(m,l) into dead rel regions; even
// group rescales, combines, divides, stores.
__global__ __launch_bounds__(512, 2) void attn_kernel(
    const __hip_bfloat16* __restrict__ Qg,   // [B][H][S][64]
    const __hip_bfloat16* __restrict__ Kg,   // [B][H][S][64] (pre-scaled 0.125*log2e)
    const __hip_bfloat16* __restrict__ VTg,  // [B][H][64][S]
    const __hip_bfloat16* __restrict__ Tg,   // [H][2048][64] (pre-scaled log2e)
    __hip_bfloat16* __restrict__ Cg) {       // [B*S][1024]
  __shared__ __align__(16) char smem[65536];   // 8 waves x 8 KB f32 rel (merge reuses)
  const int tid = threadIdx.x;
  const int wall = tid >> 6;          // 0..7
  const int g = wall >> 2;            // 0 = even kt, 1 = odd kt
  const int w = wall & 3;             // q-subtile
  const int l = tid & 63;
  const int ql = l & 31, half = l >> 5;
  char* relw = smem + wall * 8192;    // per-wave [32 q][64 kl] f32, 16B-granule XOR swizzle

  const int bx = blockIdx.x;
  const int work = (bx & 7) * 64 + (bx >> 3);   // XCD-chunk swizzle
  const int b = work & 3, hqt = work >> 2;
  const int h = hqt >> 3, qt = hqt & 7;
  const int qb = qt * 128;
  const int q0 = qb + 32 * w;

  const size_t bh = (size_t)(b * 16 + h);
  const char* Qb = (const char*)Qg + bh * 131072;
  const char* Kb = (const char*)Kg + bh * 131072;
  const char* Vb = (const char*)VTg + bh * 131072;
  const char* Tb = (const char*)Tg + (size_t)h * 262144;

  // per-lane precomputed addressing
  const int relsw = ql * 256 + ((ql & 15) << 4);          // rel row base | swizzle
  const int u4 = (ql << 2) - (half << 4);                 // 4*(ql - 4*half)

  // Q fragments (B-operand: lane holds Q[q0+ql][16*ds + 8*half + t])
  s8v qv[4];
  {
    const char* qrow = Qb + (size_t)(q0 + ql) * 128 + half * 16;
    #pragma unroll
    for (int ds = 0; ds < 4; ++ds) qv[ds] = u4_to_s8(*(const uint4*)(qrow + ds * 32));
  }

  f32x16 cacc0 = {}, cacc1 = {};        // ctx[q over regs][d = tile*32 + lane]
  float mL = -1.0e30f, lsum = 0.0f;     // per-group log2-domain running max / prob sum

  for (int s = 0; s < 8; ++s) {
    const int kt = 2 * s + g;
    const int k0 = kt * 64;
    const int rbase = qb + 960 - 64 * kt;

    // ---- V(kt) -> registers ----
    uint4 vr[8];
    { const int kn = kt * 128;
      #pragma unroll
      for (int t = 0; t < 2; ++t)
        #pragma unroll
        for (int ks = 0; ks < 4; ++ks)
          vr[t * 4 + ks] = *(const uint4*)(Vb + (size_t)(t * 32 + ql) * 2048 + kn + ks * 32 + half * 16);
    }

    // ---- REL band tiles, store order t2,t0,t1 (f32 wrap-store, r6-verbatim geometry) ----
    #pragma unroll
    for (int ti = 0; ti < 3; ++ti) {
      const int bt = (ti == 0) ? 2 : ((ti == 1) ? 0 : 1);
      const char* trow = Tb + (size_t)(rbase + 32 * (w + bt) + ql) * 128 + half * 16;
      f32x16 racc = {};
      __builtin_amdgcn_s_setprio(1);
      #pragma unroll
      for (int ds = 0; ds < 4; ++ds) {
        uint4 tf = *(const uint4*)(trow + ds * 32);
        racc = __builtin_amdgcn_mfma_f32_32x32x16_bf16(u4_to_s8(tf), qv[ds], racc, 0, 0, 0);
      }
      __builtin_amdgcn_s_setprio(0);
      #pragma unroll
      for (int g4 = 0; g4 < 4; ++g4) {
        #pragma unroll
        for (int j = 0; j < 4; ++j) {
          int pos4;
          if (bt == 2)      pos4 = (u4 + 4 * (-1 - j - 8 * g4)) & 124;
          else if (bt == 0) pos4 = ((u4 + 4 * (63 - j - 8 * g4)) & 252) | 128;
          else              pos4 = (u4 + 4 * (31 - j - 8 * g4)) & 252;
          *(float*)(relw + (relsw ^ pos4)) = racc[4 * g4 + j];
        }
      }
    }

    // ---- QK^T in log2 domain (K fragments direct from global) ----
    f32x16 p0 = {}, p1 = {};
    {
      const char* krow0 = Kb + (size_t)(k0 + ql) * 128 + half * 16;
      const char* krow1 = krow0 + 32 * 128;
      __builtin_amdgcn_s_setprio(1);
      #pragma unroll
      for (int ds = 0; ds < 4; ++ds) {
        uint4 kf0 = *(const uint4*)(krow0 + ds * 32);
        uint4 kf1 = *(const uint4*)(krow1 + ds * 32);
        p0 = __builtin_amdgcn_mfma_f32_32x32x16_bf16(u4_to_s8(kf0), qv[ds], p0, 0, 0, 0);
        p1 = __builtin_amdgcn_mfma_f32_32x32x16_bf16(u4_to_s8(kf1), qv[ds], p1, 0, 0, 0);
      }
      __builtin_amdgcn_s_setprio(0);
    }

    // ---- gather rel quads (vectorized) + add to scores ----
    #pragma unroll
    for (int mp = 0; mp < 4; ++mp) {
      const int X0 = 32 * mp + 16 * half;
      f32x4 r0 = *(const f32x4*)(relw + (relsw ^ X0));
      f32x4 r1 = *(const f32x4*)(relw + (relsw ^ (X0 + 128)));
      #pragma unroll
      for (int j = 0; j < 4; ++j) {
        p0[4 * mp + j] += r0[j];
        p1[4 * mp + j] += r1[j];
      }
    }

    // ---- online softmax (log2 domain, defer-max, tree reductions) ----
    float mx[8];
    #pragma unroll
    for (int i = 0; i < 8; ++i)
      mx[i] = fmaxf(fmaxf(p0[2 * i], p0[2 * i + 1]), fmaxf(p1[2 * i], p1[2 * i + 1]));
    float pmax = fmaxf(fmaxf(fmaxf(mx[0], mx[1]), fmaxf(mx[2], mx[3])),
                       fmaxf(fmaxf(mx[4], mx[5]), fmaxf(mx[6], mx[7])));
    pmax = fmaxf(pmax, __shfl_xor(pmax, 32));
    if (!__all(pmax - mL <= 12.0f)) {
      const float mnew = fmaxf(mL, pmax);
      const float corr = exp2_fast(mL - mnew);
      mL = mnew;
      lsum *= corr;
      #pragma unroll
      for (int r = 0; r < 16; ++r) {
        const float cr = __shfl(corr, (r & 3) + 8 * (r >> 2) + 4 * half);
        cacc0[r] *= cr;
        cacc1[r] *= cr;
      }
    }
    #pragma unroll
    for (int r = 0; r < 16; ++r) {
      p0[r] = exp2_fast(p0[r] - mL);
      p1[r] = exp2_fast(p1[r] - mL);
    }
    float sm[8];
    #pragma unroll
    for (int i = 0; i < 8; ++i)
      sm[i] = (p0[2 * i] + p0[2 * i + 1]) + (p1[2 * i] + p1[2 * i + 1]);
    float psum = ((sm[0] + sm[1]) + (sm[2] + sm[3])) + ((sm[4] + sm[5]) + (sm[6] + sm[7]));
    psum += __shfl_xor(psum, 32);
    lsum += psum;

    // ---- pack P to bf16 words, exchange halves to build PV A-fragments ----
    unsigned int w0[8], w1[8];
    #pragma unroll
    for (int jw = 0; jw < 8; ++jw) {
      w0[jw] = cvtpk(p0[2 * jw], p0[2 * jw + 1]);
      w1[jw] = cvtpk(p1[2 * jw], p1[2 * jw + 1]);
    }
    unsigned int r0x[4], r1x[4];
    #pragma unroll
    for (int i = 0; i < 4; ++i) {
      const int jkeep = (i & 1) + 4 * (i >> 1);      // {0,1,4,5}
      const int jsend = jkeep + 2;                   // {2,3,6,7}
      unsigned int v0 = half ? w0[jkeep] : w0[jsend];
      unsigned int v1 = half ? w1[jkeep] : w1[jsend];
      r0x[i] = (unsigned int)__shfl_xor((int)v0, 32);
      r1x[i] = (unsigned int)__shfl_xor((int)v1, 32);
    }

    // ---- PV: cacc[q][d] += P[q][k] * V[k][d] (V from registers) ----
    __builtin_amdgcn_s_setprio(1);
    #pragma unroll
    for (int ks = 0; ks < 4; ++ks) {
      const int mm = ks & 1;
      unsigned int f0_, f1_, f2_, f3_;
      if (ks < 2) {
        f0_ = half ? r0x[2 * mm]     : w0[4 * mm];
        f1_ = half ? r0x[2 * mm + 1] : w0[4 * mm + 1];
        f2_ = half ? w0[4 * mm + 2]  : r0x[2 * mm];
        f3_ = half ? w0[4 * mm + 3]  : r0x[2 * mm + 1];
      } else {
        f0_ = half ? r1x[2 * mm]     : w1[4 * mm];
        f1_ = half ? r1x[2 * mm + 1] : w1[4 * mm + 1];
        f2_ = half ? w1[4 * mm + 2]  : r1x[2 * mm];
        f3_ = half ? w1[4 * mm + 3]  : r1x[2 * mm + 1];
      }
      s8v pf = words_to_s8(f0_, f1_, f2_, f3_);
      cacc0 = __builtin_amdgcn_mfma_f32_32x32x16_bf16(pf, u4_to_s8(vr[ks]), cacc0, 0, 0, 0);
      cacc1 = __builtin_amdgcn_mfma_f32_32x32x16_bf16(pf, u4_to_s8(vr[4 + ks]), cacc1, 0, 0, 0);
    }
    __builtin_amdgcn_s_setprio(0);
  }

  // ---- merge: odd group writes partials into dead rel regions; even group combines ----
  __syncthreads();                       // all waves done with their own rel scratch
  if (g == 1) {
    char* xch = smem + w * 8192;         // even waves' rel regions (dead)
    #pragma unroll
    for (int c = 0; c < 4; ++c) {
      f32x4 qa  = {cacc0[4 * c], cacc0[4 * c + 1], cacc0[4 * c + 2], cacc0[4 * c + 3]};
      f32x4 qb2 = {cacc1[4 * c], cacc1[4 * c + 1], cacc1[4 * c + 2], cacc1[4 * c + 3]};
      *(f32x4*)(xch + l * 128 + ((c * 16) ^ ((l & 7) << 4))) = qa;
      *(f32x4*)(xch + l * 128 + (((c + 4) * 16) ^ ((l & 7) << 4))) = qb2;
    }
    *(float2*)(smem + 32768 + w * 512 + l * 8) = make_float2(mL, lsum);  // wave 4's rel (dead)
  }
  __syncthreads();
  if (g == 0) {
    const float2 mo = *(const float2*)(smem + 32768 + w * 512 + l * 8);
    const float mstar = fmaxf(mL, mo.x);
    const float se = exp2_fast(mL - mstar);
    const float so = exp2_fast(mo.x - mstar);
    const float lstar = lsum * se + mo.y * so;
    const char* xch = smem + w * 8192;
    f32x4 o0[4], o1[4];
    #pragma unroll
    for (int c = 0; c < 4; ++c) {
      o0[c] = *(const f32x4*)(xch + l * 128 + ((c * 16) ^ ((l & 7) << 4)));
      o1[c] = *(const f32x4*)(xch + l * 128 + (((c + 4) * 16) ^ ((l & 7) << 4)));
    }
    #pragma unroll
    for (int r = 0; r < 16; ++r) {
      const int qr = (r & 3) + 8 * (r >> 2) + 4 * half;
      const float cre = __shfl(se, qr);
      const float cro = __shfl(so, qr);
      const float inv = 1.0f / __shfl(lstar, qr);
      const float v0 = (cacc0[r] * cre + o0[r >> 2][r & 3] * cro) * inv;
      const float v1 = (cacc1[r] * cre + o1[r >> 2][r & 3] * cro) * inv;
      const size_t row = (size_t)b * 1024 + q0 + qr;
      const size_t basei = row * 1024 + h * 64 + ql;
      Cg[basei]      = __float2bfloat16(v0);
      Cg[basei + 32] = __float2bfloat16(v1);
    }
  }
}

// ---------- launcher ----------
extern "C" void kernel_launch(void* const* d_in, const int* in_sizes, int n_in,
                              void* d_out, int out_size, void* d_ws, size_t ws_size,
                              hipStream_t stream) {
  (void)in_sizes; (void)n_in; (void)out_size; (void)ws_size;
  const float* x  = (const float*)d_in[0];
  const float* wq = (const float*)d_in[1];
  const float* bq = (const float*)d_in[2];
  const float* wk = (const float*)d_in[3];
  const float* bk = (const float*)d_in[4];
  const float* wv = (const float*)d_in[5];
  const float* bv = (const float*)d_in[6];
  const float* wo = (const float*)d_in[7];
  const float* bo = (const float*)d_in[8];
  const float* tb = (const float*)d_in[9];

  char* ws = (char*)d_ws;
  __hip_bfloat16* XB   = (__hip_bfloat16*)(ws);              // [4096][1024]
  __hip_bfloat16* WQKV = (__hip_bfloat16*)(ws + 8388608);    // [3072][1024] (wq|wk|wv)
  __hip_bfloat16* WOb  = (__hip_bfloat16*)(ws + 14680064);   // [1024][1024]
  __hip_bfloat16* TBL  = (__hip_bfloat16*)(ws + 16777216);   // [16][2048][64]
  __hip_bfloat16* QB   = (__hip_bfloat16*)(ws + 20971520);   // [4][16][1024][64]
  __hip_bfloat16* KB   = (__hip_bfloat16*)(ws + 29360128);   // [4][16][1024][64]
  __hip_bfloat16* VTB  = (__hip_bfloat16*)(ws + 37748736);   // [4][16][64][1024]
  __hip_bfloat16* CTX  = (__hip_bfloat16*)(ws + 46137344);   // [4096][1024]

  cvt_fused_kernel<<<5120, 256, 0, stream>>>(x, wq, wk, wv, wo, tb, XB, WQKV, WOb, TBL);
  gemm_qkv<<<dim3(24, 32), 256, 0, stream>>>(XB, WQKV, bq, bk, bv, QB, KB, VTB);
  attn_kernel<<<512, 512, 0, stream>>>(QB, KB, VTB, TBL, CTX);
  gemm_out<<<dim3(8, 32), 256, 0, stream>>>(CTX, WOb, bo, (float*)d_out);
}

// Round 11
// 108.807 us; speedup vs baseline: 1.5545x; 1.5545x over previous
//
#include <hip/hip_runtime.h>
#include <hip/hip_bf16.h>
#include <stdint.h>

// ---------- types / helpers ----------
typedef __attribute__((ext_vector_type(8))) short s8v;      // 8 x bf16 (4 VGPR)
typedef __attribute__((ext_vector_type(4))) float f32x4;
typedef __attribute__((ext_vector_type(16))) float f32x16;

union V16 { uint4 u4; unsigned int u[4]; s8v s; };

__device__ inline s8v u4_to_s8(uint4 v) { V16 c; c.u4 = v; return c.s; }
__device__ inline s8v words_to_s8(unsigned int a, unsigned int b, unsigned int c, unsigned int d) {
  V16 t; t.u[0] = a; t.u[1] = b; t.u[2] = c; t.u[3] = d; return t.s;
}
__device__ inline unsigned short f2b(float f) {
  __hip_bfloat16 h = __float2bfloat16(f);
  unsigned short u; __builtin_memcpy(&u, &h, 2); return u;
}
__device__ inline unsigned int pack2(float lo, float hi) {
  return ((unsigned int)f2b(hi) << 16) | (unsigned int)f2b(lo);
}
// packed f32->bf16 pair (RNE), 1 instruction
__device__ inline unsigned int cvtpk(float lo, float hi) {
  unsigned int r; asm("v_cvt_pk_bf16_f32 %0, %1, %2" : "=v"(r) : "v"(lo), "v"(hi)); return r;
}
__device__ inline float exp2_fast(float x) {
#if __has_builtin(__builtin_amdgcn_exp2f)
  return __builtin_amdgcn_exp2f(x);
#else
  float y; asm("v_exp_f32 %0, %1" : "=v"(y) : "v"(x)); return y;
#endif
}
// async global->LDS, 16B per lane; LDS dest = wave-uniform base + lane*16
__device__ inline void gld16(const void* g, void* lds) {
  __builtin_amdgcn_global_load_lds((const __attribute__((address_space(1))) void*)g,
                                   (__attribute__((address_space(3))) void*)lds, 16, 0, 0);
}

#define LOG2E 1.4426950408889634f

// ---------- convert kernel: x, wq, wk, wv, wo only (table moved into gemm_qkv grid) ----------
__global__ void cvt_xw_kernel(const float* __restrict__ x, const float* __restrict__ wq,
                              const float* __restrict__ wk, const float* __restrict__ wv,
                              const float* __restrict__ wo,
                              __hip_bfloat16* __restrict__ XB, __hip_bfloat16* __restrict__ WQKV,
                              __hip_bfloat16* __restrict__ WOb) {
  size_t i = ((size_t)blockIdx.x * 256 + threadIdx.x) * 8;
  const float* src; __hip_bfloat16* dst; size_t off;
  if (i < 4194304)      { src = x;  dst = XB;             off = i; }
  else if (i < 5242880) { src = wq; dst = WQKV;           off = i - 4194304; }
  else if (i < 6291456) { src = wk; dst = WQKV + 1048576; off = i - 5242880; }
  else if (i < 7340032) { src = wv; dst = WQKV + 2097152; off = i - 6291456; }
  else                  { src = wo; dst = WOb;            off = i - 7340032; }
  const float4* s4 = (const float4*)(src + off);
  float4 a = s4[0], b = s4[1];
  uint4 o;
  o.x = pack2(a.x, a.y); o.y = pack2(a.z, a.w);
  o.z = pack2(b.x, b.y); o.w = pack2(b.z, b.w);
  *(uint4*)(dst + off) = o;
}

// ---------- QKV GEMM + fused table convert ----------
// flat grid 1792: blocks 0..767 = GEMM (n-tile = flat%24 [0-7 Q, 8-15 K, 16-23 V], m-tile =
// flat/24); blocks 768..1791 = rpe_table f32 -> TBL bf16 pre-scaled by log2e (row 2047 zero).
// The GEMM is compute-bound with L2-resident operands; table streaming rides on idle HBM BW,
// removing ~8us of previously-serial cvt time. gemm_qkv must still fully precede attn (TBL).
__global__ __launch_bounds__(256, 3) void gemm_qkv(
    const __hip_bfloat16* __restrict__ A,      // XB [4096][1024]
    const __hip_bfloat16* __restrict__ Bt,     // WQKV [3072][1024]
    const float* __restrict__ bq, const float* __restrict__ bk, const float* __restrict__ bv,
    __hip_bfloat16* __restrict__ QB, __hip_bfloat16* __restrict__ KB,
    __hip_bfloat16* __restrict__ VTB,
    const float* __restrict__ tb, __hip_bfloat16* __restrict__ TBL) {
  const int flat = blockIdx.x;
  if (flat >= 768) {
    // ---- table conversion block (no LDS, no barriers; block-uniform branch) ----
    size_t i = ((size_t)(flat - 768) * 256 + threadIdx.x) * 8;
    int h = (int)(i >> 17);
    int rem = (int)(i & 131071);
    int r = rem >> 6, c = rem & 63;
    uint4 o;
    if (r < 2047) {
      const float4* s4 = (const float4*)(tb + ((size_t)h * 9999 + r) * 64 + c);
      float4 a = s4[0], b = s4[1];
      o.x = pack2(a.x * LOG2E, a.y * LOG2E); o.y = pack2(a.z * LOG2E, a.w * LOG2E);
      o.z = pack2(b.x * LOG2E, b.y * LOG2E); o.w = pack2(b.z * LOG2E, b.w * LOG2E);
    } else { o.x = 0u; o.y = 0u; o.z = 0u; o.w = 0u; }
    *(uint4*)(TBL + i) = o;
    return;
  }

  __shared__ __align__(16) char smem[32768];
  char* As = smem;
  char* Bs = smem + 16384;
  const int tid = threadIdx.x;
  const int w = tid >> 6, l = tid & 63;
  const int wr = w >> 1, wc = w & 1;
  const int lr = l & 15, lg = l >> 4;
  const int nt = flat % 24, mt = flat / 24;
  const int m0 = mt * 128, n0 = nt * 128;

  f32x4 acc[4][4] = {};

  for (int kt = 0; kt < 16; ++kt) {
    __syncthreads();
    #pragma unroll
    for (int i = 0; i < 4; ++i) {
      const int off = i * 4096 + w * 1024;
      const int loff = off + l * 16;
      const int row = loff >> 7;
      const int cb = loff & 127;
      const int sc = cb ^ ((row & 7) << 4);
      gld16((const char*)A  + (size_t)(m0 + row) * 2048 + kt * 128 + sc, As + off);
      gld16((const char*)Bt + (size_t)(n0 + row) * 2048 + kt * 128 + sc, Bs + off);
    }
    asm volatile("s_waitcnt vmcnt(0)" ::: "memory");
    __syncthreads();
    #pragma unroll
    for (int ks = 0; ks < 2; ++ks) {
      uint4 af[4], bf4[4];
      #pragma unroll
      for (int i = 0; i < 4; ++i) {
        const int ra = wr * 64 + i * 16 + lr;
        const int rb = wc * 64 + i * 16 + lr;
        const int cb = ks * 64 + lg * 16;
        af[i]  = *(const uint4*)(As + ra * 128 + (cb ^ ((ra & 7) << 4)));
        bf4[i] = *(const uint4*)(Bs + rb * 128 + (cb ^ ((rb & 7) << 4)));
      }
      #pragma unroll
      for (int i = 0; i < 4; ++i) {
        #pragma unroll
        for (int j = 0; j < 4; ++j)
          acc[i][j] = __builtin_amdgcn_mfma_f32_16x16x32_bf16(u4_to_s8(af[i]), u4_to_s8(bf4[j]), acc[i][j], 0, 0, 0);
      }
    }
  }

  const int mrow = m0 + wr * 64 + lg * 4;
  const int ncol = n0 + wc * 64 + lr;
  const int cls = nt >> 3;            // 0 = Q, 1 = K, 2 = V (block-uniform)

  if (cls < 2) {
    const float sc = cls ? 0.125f * LOG2E : 1.0f;
    const float* bias = cls ? bk : bq;
    __hip_bfloat16* op = cls ? KB : QB;
    #pragma unroll
    for (int j = 0; j < 4; ++j) {
      const int n = ncol - cls * 1024 + j * 16;
      const float bia = bias[n];
      const int hh = n >> 6, hd = n & 63;
      #pragma unroll
      for (int i = 0; i < 4; ++i) {
        #pragma unroll
        for (int r = 0; r < 4; ++r) {
          const int m = mrow + i * 16 + r;
          const int bb = m >> 10, ss = m & 1023;
          op[(((size_t)(bb * 16 + hh)) * 1024 + ss) * 64 + hd] = __float2bfloat16((acc[i][j][r] + bia) * sc);
        }
      }
    }
  } else {
    // V: write VT [B][H][64][S]; quad of consecutive s -> one 8B store
    #pragma unroll
    for (int j = 0; j < 4; ++j) {
      const int f = ncol - 2048 + j * 16;      // v feature = h*64+hd
      const float bia = bv[f];
      const int fh = f >> 6, fd = f & 63;
      #pragma unroll
      for (int i = 0; i < 4; ++i) {
        const int m = mrow + i * 16;          // quad m..m+3, m%4==0
        const int bb = m >> 10, ss = m & 1023;
        ushort4 qv;
        qv.x = f2b(acc[i][j][0] + bia); qv.y = f2b(acc[i][j][1] + bia);
        qv.z = f2b(acc[i][j][2] + bia); qv.w = f2b(acc[i][j][3] + bia);
        *(ushort4*)((char*)VTB + (((size_t)bb * 1048576 + (size_t)fh * 65536 + fd * 1024 + ss) * 2)) = qv;
      }
    }
  }
}

// ---------- out-proj GEMM: d_out[m][n] = CTX[m]·WOb[n] + bo, f32 out ----------
__global__ __launch_bounds__(256, 3) void gemm_out(
    const __hip_bfloat16* __restrict__ A,      // CTX [4096][1024]
    const __hip_bfloat16* __restrict__ Bt,     // WOb [1024][1024]
    const float* __restrict__ bo,
    float* __restrict__ out) {
  __shared__ __align__(16) char smem[32768];
  char* As = smem;
  char* Bs = smem + 16384;
  const int tid = threadIdx.x;
  const int w = tid >> 6, l = tid & 63;
  const int wr = w >> 1, wc = w & 1;
  const int lr = l & 15, lg = l >> 4;
  const int m0 = blockIdx.y * 128, n0 = blockIdx.x * 128;

  f32x4 acc[4][4] = {};

  for (int kt = 0; kt < 16; ++kt) {
    __syncthreads();
    #pragma unroll
    for (int i = 0; i < 4; ++i) {
      const int off = i * 4096 + w * 1024;
      const int loff = off + l * 16;
      const int row = loff >> 7;
      const int cb = loff & 127;
      const int sc = cb ^ ((row & 7) << 4);
      gld16((const char*)A  + (size_t)(m0 + row) * 2048 + kt * 128 + sc, As + off);
      gld16((const char*)Bt + (size_t)(n0 + row) * 2048 + kt * 128 + sc, Bs + off);
    }
    asm volatile("s_waitcnt vmcnt(0)" ::: "memory");
    __syncthreads();
    #pragma unroll
    for (int ks = 0; ks < 2; ++ks) {
      uint4 af[4], bf4[4];
      #pragma unroll
      for (int i = 0; i < 4; ++i) {
        const int ra = wr * 64 + i * 16 + lr;
        const int rb = wc * 64 + i * 16 + lr;
        const int cb = ks * 64 + lg * 16;
        af[i]  = *(const uint4*)(As + ra * 128 + (cb ^ ((ra & 7) << 4)));
        bf4[i] = *(const uint4*)(Bs + rb * 128 + (cb ^ ((rb & 7) << 4)));
      }
      #pragma unroll
      for (int i = 0; i < 4; ++i) {
        #pragma unroll
        for (int j = 0; j < 4; ++j)
          acc[i][j] = __builtin_amdgcn_mfma_f32_16x16x32_bf16(u4_to_s8(af[i]), u4_to_s8(bf4[j]), acc[i][j], 0, 0, 0);
      }
    }
  }

  const int mrow = m0 + wr * 64 + lg * 4;
  const int ncol = n0 + wc * 64 + lr;
  #pragma unroll
  for (int j = 0; j < 4; ++j) {
    const int n = ncol + j * 16;
    const float bia = bo[n];
    #pragma unroll
    for (int i = 0; i < 4; ++i) {
      #pragma unroll
      for (int r = 0; r < 4; ++r) {
        const int m = mrow + i * 16 + r;
        out[(size_t)m * 1024 + n] = acc[i][j][r] + bia;
      }
    }
  }
}

// ---------- fused attention with RPE (r6-verbatim: proven fastest passing structure) ----------
// grid 512 (XCD-chunk swizzled), 256 threads = 4 waves, 32 q-rows/wave.
// LDS 64 KB = K 8K (single) + T ring-3 24K + rel f32 4x8K -> 2 blocks/CU.
// Per kt (2 barriers): [bar] stage K(kt)+T chunk(kt) [vmcnt(0)][bar] | V(kt)->regs (plain
// loads) | REL (store t2,t0,t1) | QK^T | gather+softmax | PV.
// REL cache: band tile t at kt covers same global rows as tile t+2 at kt+1 -> keep racc0
// in regs, reuse as next kt's racc2. REL MFMAs 12 -> 8 per kt (kt>0).
// Wrap-store (branchless, verified): order t2,t0,t1; positions t2:(4kl)&124,
// t0:((4kl)&252)|128, t1:(4kl)&252; all garbage lands where a later tile writes valid
// (garbage and overwriter provably share the same lane -> same-lane DS ordering).
__global__ __launch_bounds__(256, 2) void attn_kernel(
    const __hip_bfloat16* __restrict__ Qg,   // [B][H][S][64]
    const __hip_bfloat16* __restrict__ Kg,   // [B][H][S][64] (pre-scaled 0.125*log2e)
    const __hip_bfloat16* __restrict__ VTg,  // [B][H][64][S]
    const __hip_bfloat16* __restrict__ Tg,   // [H][2048][64] (pre-scaled log2e)
    __hip_bfloat16* __restrict__ Cg) {       // [B*S][1024]
  __shared__ __align__(16) char smem[65536];
  char* Klds = smem;                 // 8 KB single buffer (swizzled)
  char* Tlds = smem + 8192;          // 3 x 8 KB ring (swizzled)
  const int tid = threadIdx.x;
  const int w = tid >> 6, l = tid & 63;
  const int ql = l & 31, half = l >> 5;
  char* relw = smem + 32768 + w * 8192;  // per-wave [32 q][64 kl] f32, 16B-granule XOR swizzle

  const int bx = blockIdx.x;
  const int work = (bx & 7) * 64 + (bx >> 3);   // XCD-chunk swizzle
  const int b = work & 3, hqt = work >> 2;
  const int h = hqt >> 3, qt = hqt & 7;
  const int qb = qt * 128;
  const int q0 = qb + 32 * w;

  const size_t bh = (size_t)(b * 16 + h);
  const char* Qb = (const char*)Qg + bh * 131072;
  const char* Kb = (const char*)Kg + bh * 131072;
  const char* Vb = (const char*)VTg + bh * 131072;
  const char* Tb = (const char*)Tg + (size_t)h * 262144;

  // per-lane precomputed addressing
  const int relsw = ql * 256 + ((ql & 15) << 4);          // rel row base | swizzle
  const int u4 = (ql << 2) - (half << 4);                 // 4*(ql - 4*half)
  const int k0sw = ql * 128 + ((ql & 7) << 4);            // K row ql, swizzled
  const int k1sw = (32 + ql) * 128 + ((ql & 7) << 4);     // K row 32+ql

  auto stageK = [&](int k0n) {
    #pragma unroll
    for (int i = 0; i < 2; ++i) {
      const int loff = i * 4096 + w * 1024 + l * 16;
      const int row = loff >> 7, cb = loff & 127;
      const int sc = cb ^ ((row & 7) << 4);
      gld16(Kb + (size_t)(k0n + row) * 128 + sc, Klds + i * 4096 + w * 1024);
    }
  };
  auto stageT = [&](int rsrc) {
    const int slot = (int)(((unsigned)(rsrc >> 6)) % 3u);
    char* dst = Tlds + slot * 8192;
    #pragma unroll
    for (int i = 0; i < 2; ++i) {
      const int loff = i * 4096 + w * 1024 + l * 16;
      const int row = loff >> 7, cb = loff & 127;
      const int sc = cb ^ ((row & 7) << 4);
      gld16(Tb + (size_t)(rsrc + row) * 128 + sc, dst + i * 4096 + w * 1024);
    }
  };

  // Q fragments (B-operand: lane holds Q[q0+ql][16*ds + 8*half + t])
  s8v qv[4];
  {
    const char* qrow = Qb + (size_t)(q0 + ql) * 128 + half * 16;
    #pragma unroll
    for (int ds = 0; ds < 4; ++ds) qv[ds] = u4_to_s8(*(const uint4*)(qrow + ds * 32));
  }

  f32x16 cacc0 = {}, cacc1 = {};        // ctx[q over regs][d = tile*32 + lane]
  f32x16 rcache = {};                   // REL tile (w,0) of previous kt == (w,2) of this kt
  float mL = -1.0e30f, lsum = 0.0f;     // log2-domain running max / prob sum
  int rbase = qb + 960;                 // table band base row for kt=0 (dec 64/kt; min qb >= 0)

  for (int kt = 0; kt < 16; ++kt, rbase -= 64) {
    __syncthreads();                    // all LDS reads of kt-1 done
    stageK(kt * 64);
    stageT(rbase);                      // chunk c; c+1, c+2 staged at earlier kts
    if (kt == 0) { stageT(rbase + 64); stageT(rbase + 128); }
    asm volatile("s_waitcnt vmcnt(0)" ::: "memory");
    __syncthreads();                    // K(kt), T window ready

    // ---- V(kt) -> registers (plain loads; compiler places the waitcnt before PV) ----
    uint4 vr[8];
    { const int kn = kt * 128;
      #pragma unroll
      for (int t = 0; t < 2; ++t)
        #pragma unroll
        for (int ks = 0; ks < 4; ++ks)
          vr[t * 4 + ks] = *(const uint4*)(Vb + (size_t)(t * 32 + ql) * 2048 + kn + ks * 32 + half * 16);
    }

    // ---- REL band tiles: t2 (cached for kt>0), then t0, then t1; store order t2,t0,t1 ----
    auto relTile = [&](int bt) {
      const int slot = (int)(((unsigned)(rbase >> 6) + (unsigned)((w + bt) >> 1)) % 3u);
      const int rowin = ((w + bt) & 1) * 32 + ql;
      const int tbsw = slot * 8192 + rowin * 128 + ((ql & 7) << 4);
      f32x16 racc = {};
      __builtin_amdgcn_s_setprio(1);
      #pragma unroll
      for (int ds = 0; ds < 4; ++ds) {
        const int cb = ds * 32 + half * 16;
        uint4 tf = *(const uint4*)(Tlds + (tbsw ^ cb));
        racc = __builtin_amdgcn_mfma_f32_32x32x16_bf16(u4_to_s8(tf), qv[ds], racc, 0, 0, 0);
      }
      __builtin_amdgcn_s_setprio(0);
      return racc;
    };

    f32x16 racc2 = (kt == 0) ? relTile(2) : rcache;
    #pragma unroll
    for (int g = 0; g < 4; ++g)
      #pragma unroll
      for (int j = 0; j < 4; ++j) {
        const int pos4 = (u4 + 4 * (-1 - j - 8 * g)) & 124;
        *(float*)(relw + (relsw ^ pos4)) = racc2[4 * g + j];
      }
    f32x16 racc0 = relTile(0);
    #pragma unroll
    for (int g = 0; g < 4; ++g)
      #pragma unroll
      for (int j = 0; j < 4; ++j) {
        const int pos4 = ((u4 + 4 * (63 - j - 8 * g)) & 252) | 128;
        *(float*)(relw + (relsw ^ pos4)) = racc0[4 * g + j];
      }
    rcache = racc0;
    f32x16 racc1 = relTile(1);
    #pragma unroll
    for (int g = 0; g < 4; ++g)
      #pragma unroll
      for (int j = 0; j < 4; ++j) {
        const int pos4 = (u4 + 4 * (31 - j - 8 * g)) & 252;
        *(float*)(relw + (relsw ^ pos4)) = racc1[4 * g + j];
      }

    // ---- QK^T in log2 domain (independent of rel; overlaps the LDS write->read latency) ----
    f32x16 p0 = {}, p1 = {};
    __builtin_amdgcn_s_setprio(1);
    #pragma unroll
    for (int ds = 0; ds < 4; ++ds) {
      const int cb = ds * 32 + half * 16;
      uint4 kf0 = *(const uint4*)(Klds + (k0sw ^ cb));
      uint4 kf1 = *(const uint4*)(Klds + (k1sw ^ cb));
      p0 = __builtin_amdgcn_mfma_f32_32x32x16_bf16(u4_to_s8(kf0), qv[ds], p0, 0, 0, 0);
      p1 = __builtin_amdgcn_mfma_f32_32x32x16_bf16(u4_to_s8(kf1), qv[ds], p1, 0, 0, 0);
    }
    __builtin_amdgcn_s_setprio(0);

    // ---- gather rel quads (vectorized) + add to scores ----
    #pragma unroll
    for (int mp = 0; mp < 4; ++mp) {
      const int X0 = 32 * mp + 16 * half;
      f32x4 r0 = *(const f32x4*)(relw + (relsw ^ X0));
      f32x4 r1 = *(const f32x4*)(relw + (relsw ^ (X0 + 128)));
      #pragma unroll
      for (int j = 0; j < 4; ++j) {
        p0[4 * mp + j] += r0[j];
        p1[4 * mp + j] += r1[j];
      }
    }

    // ---- online softmax (log2 domain, defer-max, tree reductions) ----
    float mx[8];
    #pragma unroll
    for (int i = 0; i < 8; ++i)
      mx[i] = fmaxf(fmaxf(p0[2 * i], p0[2 * i + 1]), fmaxf(p1[2 * i], p1[2 * i + 1]));
    float pmax = fmaxf(fmaxf(fmaxf(mx[0], mx[1]), fmaxf(mx[2], mx[3])),
                       fmaxf(fmaxf(mx[4], mx[5]), fmaxf(mx[6], mx[7])));
    pmax = fmaxf(pmax, __shfl_xor(pmax, 32));
    if (!__all(pmax - mL <= 12.0f)) {
      const float mnew = fmaxf(mL, pmax);
      const float corr = exp2_fast(mL - mnew);
      mL = mnew;
      lsum *= corr;
      #pragma unroll
      for (int r = 0; r < 16; ++r) {
        const float cr = __shfl(corr, (r & 3) + 8 * (r >> 2) + 4 * half);
        cacc0[r] *= cr;
        cacc1[r] *= cr;
      }
    }
    #pragma unroll
    for (int r = 0; r < 16; ++r) {
      p0[r] = exp2_fast(p0[r] - mL);
      p1[r] = exp2_fast(p1[r] - mL);
    }
    float sm[8];
    #pragma unroll
    for (int i = 0; i < 8; ++i)
      sm[i] = (p0[2 * i] + p0[2 * i + 1]) + (p1[2 * i] + p1[2 * i + 1]);
    float psum = ((sm[0] + sm[1]) + (sm[2] + sm[3])) + ((sm[4] + sm[5]) + (sm[6] + sm[7]));
    psum += __shfl_xor(psum, 32);
    lsum += psum;

    // ---- pack P to bf16 words, exchange halves to build PV A-fragments ----
    unsigned int w0[8], w1[8];
    #pragma unroll
    for (int jw = 0; jw < 8; ++jw) {
      w0[jw] = cvtpk(p0[2 * jw], p0[2 * jw + 1]);
      w1[jw] = cvtpk(p1[2 * jw], p1[2 * jw + 1]);
    }
    unsigned int r0x[4], r1x[4];
    #pragma unroll
    for (int i = 0; i < 4; ++i) {
      const int jkeep = (i & 1) + 4 * (i >> 1);      // {0,1,4,5}
      const int jsend = jkeep + 2;                   // {2,3,6,7}
      unsigned int v0 = half ? w0[jkeep] : w0[jsend];
      unsigned int v1 = half ? w1[jkeep] : w1[jsend];
      r0x[i] = (unsigned int)__shfl_xor((int)v0, 32);
      r1x[i] = (unsigned int)__shfl_xor((int)v1, 32);
    }

    // ---- PV: cacc[q][d] += P[q][k] * V[k][d] (V from registers) ----
    __builtin_amdgcn_s_setprio(1);
    #pragma unroll
    for (int ks = 0; ks < 4; ++ks) {
      const int mm = ks & 1;
      unsigned int f0_, f1_, f2_, f3_;
      if (ks < 2) {
        f0_ = half ? r0x[2 * mm]     : w0[4 * mm];
        f1_ = half ? r0x[2 * mm + 1] : w0[4 * mm + 1];
        f2_ = half ? w0[4 * mm + 2]  : r0x[2 * mm];
        f3_ = half ? w0[4 * mm + 3]  : r0x[2 * mm + 1];
      } else {
        f0_ = half ? r1x[2 * mm]     : w1[4 * mm];
        f1_ = half ? r1x[2 * mm + 1] : w1[4 * mm + 1];
        f2_ = half ? w1[4 * mm + 2]  : r1x[2 * mm];
        f3_ = half ? w1[4 * mm + 3]  : r1x[2 * mm + 1];
      }
      s8v pf = words_to_s8(f0_, f1_, f2_, f3_);
      cacc0 = __builtin_amdgcn_mfma_f32_32x32x16_bf16(pf, u4_to_s8(vr[ks]), cacc0, 0, 0, 0);
      cacc1 = __builtin_amdgcn_mfma_f32_32x32x16_bf16(pf, u4_to_s8(vr[4 + ks]), cacc1, 0, 0, 0);
    }
    __builtin_amdgcn_s_setprio(0);
  }

  // ---- epilogue: divide by row sum, store ctx bf16 (coalesced along d=lane) ----
  #pragma unroll
  for (int r = 0; r < 16; ++r) {
    const int qr = (r & 3) + 8 * (r >> 2) + 4 * half;
    const float inv = 1.0f / __shfl(lsum, qr);
    const size_t row = (size_t)b * 1024 + q0 + qr;
    const size_t basei = row * 1024 + h * 64 + ql;
    Cg[basei]      = __float2bfloat16(cacc0[r] * inv);
    Cg[basei + 32] = __float2bfloat16(cacc1[r] * inv);
  }
}

// ---------- launcher ----------
extern "C" void kernel_launch(void* const* d_in, const int* in_sizes, int n_in,
                              void* d_out, int out_size, void* d_ws, size_t ws_size,
                              hipStream_t stream) {
  (void)in_sizes; (void)n_in; (void)out_size; (void)ws_size;
  const float* x  = (const float*)d_in[0];
  const float* wq = (const float*)d_in[1];
  const float* bq = (const float*)d_in[2];
  const float* wk = (const float*)d_in[3];
  const float* bk = (const float*)d_in[4];
  const float* wv = (const float*)d_in[5];
  const float* bv = (const float*)d_in[6];
  const float* wo = (const float*)d_in[7];
  const float* bo = (const float*)d_in[8];
  const float* tb = (const float*)d_in[9];

  char* ws = (char*)d_ws;
  __hip_bfloat16* XB   = (__hip_bfloat16*)(ws);              // [4096][1024]
  __hip_bfloat16* WQKV = (__hip_bfloat16*)(ws + 8388608);    // [3072][1024] (wq|wk|wv)
  __hip_bfloat16* WOb  = (__hip_bfloat16*)(ws + 14680064);   // [1024][1024]
  __hip_bfloat16* TBL  = (__hip_bfloat16*)(ws + 16777216);   // [16][2048][64]
  __hip_bfloat16* QB   = (__hip_bfloat16*)(ws + 20971520);   // [4][16][1024][64]
  __hip_bfloat16* KB   = (__hip_bfloat16*)(ws + 29360128);   // [4][16][1024][64]
  __hip_bfloat16* VTB  = (__hip_bfloat16*)(ws + 37748736);   // [4][16][64][1024]
  __hip_bfloat16* CTX  = (__hip_bfloat16*)(ws + 46137344);   // [4096][1024]

  cvt_xw_kernel<<<4096, 256, 0, stream>>>(x, wq, wk, wv, wo, XB, WQKV, WOb);
  gemm_qkv<<<1792, 256, 0, stream>>>(XB, WQKV, bq, bk, bv, QB, KB, VTB, tb, TBL);
  attn_kernel<<<512, 256, 0, stream>>>(QB, KB, VTB, TBL, CTX);
  gemm_out<<<dim3(8, 32), 256, 0, stream>>>(CTX, WOb, bo, (float*)d_out);
}

// Round 12
// 105.006 us; speedup vs baseline: 1.6108x; 1.0362x over previous
//
#include <hip/hip_runtime.h>
#include <hip/hip_bf16.h>
#include <stdint.h>

// ---------- types / helpers ----------
typedef __attribute__((ext_vector_type(8))) short s8v;      // 8 x bf16 (4 VGPR)
typedef __attribute__((ext_vector_type(4))) float f32x4;
typedef __attribute__((ext_vector_type(16))) float f32x16;

union V16 { uint4 u4; unsigned int u[4]; s8v s; };

__device__ inline s8v u4_to_s8(uint4 v) { V16 c; c.u4 = v; return c.s; }
__device__ inline s8v words_to_s8(unsigned int a, unsigned int b, unsigned int c, unsigned int d) {
  V16 t; t.u[0] = a; t.u[1] = b; t.u[2] = c; t.u[3] = d; return t.s;
}
__device__ inline unsigned short f2b(float f) {
  __hip_bfloat16 h = __float2bfloat16(f);
  unsigned short u; __builtin_memcpy(&u, &h, 2); return u;
}
__device__ inline unsigned int pack2(float lo, float hi) {
  return ((unsigned int)f2b(hi) << 16) | (unsigned int)f2b(lo);
}
// packed f32->bf16 pair (RNE), 1 instruction
__device__ inline unsigned int cvtpk(float lo, float hi) {
  unsigned int r; asm("v_cvt_pk_bf16_f32 %0, %1, %2" : "=v"(r) : "v"(lo), "v"(hi)); return r;
}
__device__ inline float exp2_fast(float x) {
#if __has_builtin(__builtin_amdgcn_exp2f)
  return __builtin_amdgcn_exp2f(x);
#else
  float y; asm("v_exp_f32 %0, %1" : "=v"(y) : "v"(x)); return y;
#endif
}
// async global->LDS, 16B per lane; LDS dest = wave-uniform base + lane*16
__device__ inline void gld16(const void* g, void* lds) {
  __builtin_amdgcn_global_load_lds((const __attribute__((address_space(1))) void*)g,
                                   (__attribute__((address_space(3))) void*)lds, 16, 0, 0);
}

#define LOG2E 1.4426950408889634f

// ---------- convert kernel: x, wq, wk, wv, wo only (table rides in gemm_qkv grid) ----------
__global__ void cvt_xw_kernel(const float* __restrict__ x, const float* __restrict__ wq,
                              const float* __restrict__ wk, const float* __restrict__ wv,
                              const float* __restrict__ wo,
                              __hip_bfloat16* __restrict__ XB, __hip_bfloat16* __restrict__ WQKV,
                              __hip_bfloat16* __restrict__ WOb) {
  size_t i = ((size_t)blockIdx.x * 256 + threadIdx.x) * 8;
  const float* src; __hip_bfloat16* dst; size_t off;
  if (i < 4194304)      { src = x;  dst = XB;             off = i; }
  else if (i < 5242880) { src = wq; dst = WQKV;           off = i - 4194304; }
  else if (i < 6291456) { src = wk; dst = WQKV + 1048576; off = i - 5242880; }
  else if (i < 7340032) { src = wv; dst = WQKV + 2097152; off = i - 6291456; }
  else                  { src = wo; dst = WOb;            off = i - 7340032; }
  const float4* s4 = (const float4*)(src + off);
  float4 a = s4[0], b = s4[1];
  uint4 o;
  o.x = pack2(a.x, a.y); o.y = pack2(a.z, a.w);
  o.z = pack2(b.x, b.y); o.w = pack2(b.z, b.w);
  *(uint4*)(dst + off) = o;
}

// ---------- QKV GEMM + fused table convert ----------
// flat grid 1792: blocks 0..767 = GEMM (XCD-swizzled: wg=(g%8)*96+g/8 -> each XCD owns
// 4 m-tiles x 24 n-tiles; A panel traffic/XCD 8MB->1MB), n-tile = wg%24 [0-7 Q, 8-15 K,
// 16-23 V], m-tile = wg/24; blocks 768..1791 = rpe_table f32 -> TBL bf16 (log2e-scaled).
__global__ __launch_bounds__(256, 3) void gemm_qkv(
    const __hip_bfloat16* __restrict__ A,      // XB [4096][1024]
    const __hip_bfloat16* __restrict__ Bt,     // WQKV [3072][1024]
    const float* __restrict__ bq, const float* __restrict__ bk, const float* __restrict__ bv,
    __hip_bfloat16* __restrict__ QB, __hip_bfloat16* __restrict__ KB,
    __hip_bfloat16* __restrict__ VTB,
    const float* __restrict__ tb, __hip_bfloat16* __restrict__ TBL) {
  const int flat = blockIdx.x;
  if (flat >= 768) {
    // ---- table conversion block (no LDS, no barriers; block-uniform branch) ----
    size_t i = ((size_t)(flat - 768) * 256 + threadIdx.x) * 8;
    int h = (int)(i >> 17);
    int rem = (int)(i & 131071);
    int r = rem >> 6, c = rem & 63;
    uint4 o;
    if (r < 2047) {
      const float4* s4 = (const float4*)(tb + ((size_t)h * 9999 + r) * 64 + c);
      float4 a = s4[0], b = s4[1];
      o.x = pack2(a.x * LOG2E, a.y * LOG2E); o.y = pack2(a.z * LOG2E, a.w * LOG2E);
      o.z = pack2(b.x * LOG2E, b.y * LOG2E); o.w = pack2(b.z * LOG2E, b.w * LOG2E);
    } else { o.x = 0u; o.y = 0u; o.z = 0u; o.w = 0u; }
    *(uint4*)(TBL + i) = o;
    return;
  }

  __shared__ __align__(16) char smem[32768];
  char* As = smem;
  char* Bs = smem + 16384;
  const int tid = threadIdx.x;
  const int w = tid >> 6, l = tid & 63;
  const int wr = w >> 1, wc = w & 1;
  const int lr = l & 15, lg = l >> 4;
  const int wg = (flat & 7) * 96 + (flat >> 3);   // bijective XCD swizzle (768 % 8 == 0)
  const int nt = wg % 24, mt = wg / 24;
  const int m0 = mt * 128, n0 = nt * 128;

  f32x4 acc[4][4] = {};

  for (int kt = 0; kt < 16; ++kt) {
    __syncthreads();
    #pragma unroll
    for (int i = 0; i < 4; ++i) {
      const int off = i * 4096 + w * 1024;
      const int loff = off + l * 16;
      const int row = loff >> 7;
      const int cb = loff & 127;
      const int sc = cb ^ ((row & 7) << 4);
      gld16((const char*)A  + (size_t)(m0 + row) * 2048 + kt * 128 + sc, As + off);
      gld16((const char*)Bt + (size_t)(n0 + row) * 2048 + kt * 128 + sc, Bs + off);
    }
    asm volatile("s_waitcnt vmcnt(0)" ::: "memory");
    __syncthreads();
    #pragma unroll
    for (int ks = 0; ks < 2; ++ks) {
      uint4 af[4], bf4[4];
      #pragma unroll
      for (int i = 0; i < 4; ++i) {
        const int ra = wr * 64 + i * 16 + lr;
        const int rb = wc * 64 + i * 16 + lr;
        const int cb = ks * 64 + lg * 16;
        af[i]  = *(const uint4*)(As + ra * 128 + (cb ^ ((ra & 7) << 4)));
        bf4[i] = *(const uint4*)(Bs + rb * 128 + (cb ^ ((rb & 7) << 4)));
      }
      #pragma unroll
      for (int i = 0; i < 4; ++i) {
        #pragma unroll
        for (int j = 0; j < 4; ++j)
          acc[i][j] = __builtin_amdgcn_mfma_f32_16x16x32_bf16(u4_to_s8(af[i]), u4_to_s8(bf4[j]), acc[i][j], 0, 0, 0);
      }
    }
  }

  const int mrow = m0 + wr * 64 + lg * 4;
  const int ncol = n0 + wc * 64 + lr;
  const int cls = nt >> 3;            // 0 = Q, 1 = K, 2 = V (block-uniform)

  if (cls < 2) {
    const float sc = cls ? 0.125f * LOG2E : 1.0f;
    const float* bias = cls ? bk : bq;
    __hip_bfloat16* op = cls ? KB : QB;
    #pragma unroll
    for (int j = 0; j < 4; ++j) {
      const int n = ncol - cls * 1024 + j * 16;
      const float bia = bias[n];
      const int hh = n >> 6, hd = n & 63;
      #pragma unroll
      for (int i = 0; i < 4; ++i) {
        #pragma unroll
        for (int r = 0; r < 4; ++r) {
          const int m = mrow + i * 16 + r;
          const int bb = m >> 10, ss = m & 1023;
          op[(((size_t)(bb * 16 + hh)) * 1024 + ss) * 64 + hd] = __float2bfloat16((acc[i][j][r] + bia) * sc);
        }
      }
    }
  } else {
    // V: write VT [B][H][64][S]; quad of consecutive s -> one 8B store
    #pragma unroll
    for (int j = 0; j < 4; ++j) {
      const int f = ncol - 2048 + j * 16;      // v feature = h*64+hd
      const float bia = bv[f];
      const int fh = f >> 6, fd = f & 63;
      #pragma unroll
      for (int i = 0; i < 4; ++i) {
        const int m = mrow + i * 16;          // quad m..m+3, m%4==0
        const int bb = m >> 10, ss = m & 1023;
        ushort4 qv;
        qv.x = f2b(acc[i][j][0] + bia); qv.y = f2b(acc[i][j][1] + bia);
        qv.z = f2b(acc[i][j][2] + bia); qv.w = f2b(acc[i][j][3] + bia);
        *(ushort4*)((char*)VTB + (((size_t)bb * 1048576 + (size_t)fh * 65536 + fd * 1024 + ss) * 2)) = qv;
      }
    }
  }
}

// ---------- out-proj GEMM: d_out[m][n] = CTX[m]·WOb[n] + bo, f32 out ----------
// Re-tiled 128x64 (was 128x128 at 256 blocks = 1 block/CU = 1 wave/SIMD, worst-case
// latency hiding). Flat grid 512 (XCD-swizzled, 512%8==0) -> 2 blocks/CU = 8 waves/CU;
// per XCD: 4 m-rows x all 16 n-tiles -> A panels 1MB/XCD, WOb 2MB fits per-XCD L2.
// 4 waves as 2(M-64) x 2(N-32); per wave acc[4][2]; LDS 24KB (A 16K + B 8K).
__global__ __launch_bounds__(256, 3) void gemm_out(
    const __hip_bfloat16* __restrict__ A,      // CTX [4096][1024]
    const __hip_bfloat16* __restrict__ Bt,     // WOb [1024][1024]
    const float* __restrict__ bo,
    float* __restrict__ out) {
  __shared__ __align__(16) char smem[24576];
  char* As = smem;
  char* Bs = smem + 16384;
  const int tid = threadIdx.x;
  const int w = tid >> 6, l = tid & 63;
  const int wr = w >> 1, wc = w & 1;
  const int lr = l & 15, lg = l >> 4;
  const int flat = blockIdx.x;
  const int wg = (flat & 7) * 64 + (flat >> 3);   // bijective XCD swizzle (512 % 8 == 0)
  const int nt = wg & 15, mt = wg >> 4;
  const int m0 = mt * 128, n0 = nt * 64;

  f32x4 acc[4][2] = {};

  for (int kt = 0; kt < 16; ++kt) {
    __syncthreads();
    #pragma unroll
    for (int i = 0; i < 4; ++i) {
      const int off = i * 4096 + w * 1024;
      const int loff = off + l * 16;
      const int row = loff >> 7;
      const int cb = loff & 127;
      const int sc = cb ^ ((row & 7) << 4);
      gld16((const char*)A + (size_t)(m0 + row) * 2048 + kt * 128 + sc, As + off);
    }
    #pragma unroll
    for (int i = 0; i < 2; ++i) {
      const int off = i * 4096 + w * 1024;
      const int loff = off + l * 16;
      const int row = loff >> 7;
      const int cb = loff & 127;
      const int sc = cb ^ ((row & 7) << 4);
      gld16((const char*)Bt + (size_t)(n0 + row) * 2048 + kt * 128 + sc, Bs + off);
    }
    asm volatile("s_waitcnt vmcnt(0)" ::: "memory");
    __syncthreads();
    #pragma unroll
    for (int ks = 0; ks < 2; ++ks) {
      uint4 af[4], bf2[2];
      #pragma unroll
      for (int i = 0; i < 4; ++i) {
        const int ra = wr * 64 + i * 16 + lr;
        const int cb = ks * 64 + lg * 16;
        af[i] = *(const uint4*)(As + ra * 128 + (cb ^ ((ra & 7) << 4)));
      }
      #pragma unroll
      for (int j = 0; j < 2; ++j) {
        const int rb = wc * 32 + j * 16 + lr;
        const int cb = ks * 64 + lg * 16;
        bf2[j] = *(const uint4*)(Bs + rb * 128 + (cb ^ ((rb & 7) << 4)));
      }
      #pragma unroll
      for (int i = 0; i < 4; ++i) {
        #pragma unroll
        for (int j = 0; j < 2; ++j)
          acc[i][j] = __builtin_amdgcn_mfma_f32_16x16x32_bf16(u4_to_s8(af[i]), u4_to_s8(bf2[j]), acc[i][j], 0, 0, 0);
      }
    }
  }

  const int mrow = m0 + wr * 64 + lg * 4;
  const int ncol = n0 + wc * 32 + lr;
  #pragma unroll
  for (int j = 0; j < 2; ++j) {
    const int n = ncol + j * 16;
    const float bia = bo[n];
    #pragma unroll
    for (int i = 0; i < 4; ++i) {
      #pragma unroll
      for (int r = 0; r < 4; ++r) {
        const int m = mrow + i * 16 + r;
        out[(size_t)m * 1024 + n] = acc[i][j][r] + bia;
      }
    }
  }
}

// ---------- fused attention with RPE (r6-verbatim: proven fastest passing structure) ----------
// grid 512 (XCD-chunk swizzled), 256 threads = 4 waves, 32 q-rows/wave.
// LDS 64 KB = K 8K (single) + T ring-3 24K + rel f32 4x8K -> 2 blocks/CU.
// Per kt (2 barriers): [bar] stage K(kt)+T chunk(kt) [vmcnt(0)][bar] | V(kt)->regs (plain
// loads) | REL (store t2,t0,t1) | QK^T | gather+softmax | PV.
// REL cache: band tile t at kt covers same global rows as tile t+2 at kt+1 -> keep racc0
// in regs, reuse as next kt's racc2. REL MFMAs 12 -> 8 per kt (kt>0).
// Wrap-store (branchless, verified): order t2,t0,t1; positions t2:(4kl)&124,
// t0:((4kl)&252)|128, t1:(4kl)&252.
__global__ __launch_bounds__(256, 2) void attn_kernel(
    const __hip_bfloat16* __restrict__ Qg,   // [B][H][S][64]
    const __hip_bfloat16* __restrict__ Kg,   // [B][H][S][64] (pre-scaled 0.125*log2e)
    const __hip_bfloat16* __restrict__ VTg,  // [B][H][64][S]
    const __hip_bfloat16* __restrict__ Tg,   // [H][2048][64] (pre-scaled log2e)
    __hip_bfloat16* __restrict__ Cg) {       // [B*S][1024]
  __shared__ __align__(16) char smem[65536];
  char* Klds = smem;                 // 8 KB single buffer (swizzled)
  char* Tlds = smem + 8192;          // 3 x 8 KB ring (swizzled)
  const int tid = threadIdx.x;
  const int w = tid >> 6, l = tid & 63;
  const int ql = l & 31, half = l >> 5;
  char* relw = smem + 32768 + w * 8192;  // per-wave [32 q][64 kl] f32, 16B-granule XOR swizzle

  const int bx = blockIdx.x;
  const int work = (bx & 7) * 64 + (bx >> 3);   // XCD-chunk swizzle
  const int b = work & 3, hqt = work >> 2;
  const int h = hqt >> 3, qt = hqt & 7;
  const int qb = qt * 128;
  const int q0 = qb + 32 * w;

  const size_t bh = (size_t)(b * 16 + h);
  const char* Qb = (const char*)Qg + bh * 131072;
  const char* Kb = (const char*)Kg + bh * 131072;
  const char* Vb = (const char*)VTg + bh * 131072;
  const char* Tb = (const char*)Tg + (size_t)h * 262144;

  // per-lane precomputed addressing
  const int relsw = ql * 256 + ((ql & 15) << 4);          // rel row base | swizzle
  const int u4 = (ql << 2) - (half << 4);                 // 4*(ql - 4*half)
  const int k0sw = ql * 128 + ((ql & 7) << 4);            // K row ql, swizzled
  const int k1sw = (32 + ql) * 128 + ((ql & 7) << 4);     // K row 32+ql

  auto stageK = [&](int k0n) {
    #pragma unroll
    for (int i = 0; i < 2; ++i) {
      const int loff = i * 4096 + w * 1024 + l * 16;
      const int row = loff >> 7, cb = loff & 127;
      const int sc = cb ^ ((row & 7) << 4);
      gld16(Kb + (size_t)(k0n + row) * 128 + sc, Klds + i * 4096 + w * 1024);
    }
  };
  auto stageT = [&](int rsrc) {
    const int slot = (int)(((unsigned)(rsrc >> 6)) % 3u);
    char* dst = Tlds + slot * 8192;
    #pragma unroll
    for (int i = 0; i < 2; ++i) {
      const int loff = i * 4096 + w * 1024 + l * 16;
      const int row = loff >> 7, cb = loff & 127;
      const int sc = cb ^ ((row & 7) << 4);
      gld16(Tb + (size_t)(rsrc + row) * 128 + sc, dst + i * 4096 + w * 1024);
    }
  };

  // Q fragments (B-operand: lane holds Q[q0+ql][16*ds + 8*half + t])
  s8v qv[4];
  {
    const char* qrow = Qb + (size_t)(q0 + ql) * 128 + half * 16;
    #pragma unroll
    for (int ds = 0; ds < 4; ++ds) qv[ds] = u4_to_s8(*(const uint4*)(qrow + ds * 32));
  }

  f32x16 cacc0 = {}, cacc1 = {};        // ctx[q over regs][d = tile*32 + lane]
  f32x16 rcache = {};                   // REL tile (w,0) of previous kt == (w,2) of this kt
  float mL = -1.0e30f, lsum = 0.0f;     // log2-domain running max / prob sum
  int rbase = qb + 960;                 // table band base row for kt=0 (dec 64/kt; min qb >= 0)

  for (int kt = 0; kt < 16; ++kt, rbase -= 64) {
    __syncthreads();                    // all LDS reads of kt-1 done
    stageK(kt * 64);
    stageT(rbase);                      // chunk c; c+1, c+2 staged at earlier kts
    if (kt == 0) { stageT(rbase + 64); stageT(rbase + 128); }
    asm volatile("s_waitcnt vmcnt(0)" ::: "memory");
    __syncthreads();                    // K(kt), T window ready

    // ---- V(kt) -> registers (plain loads; compiler places the waitcnt before PV) ----
    uint4 vr[8];
    { const int kn = kt * 128;
      #pragma unroll
      for (int t = 0; t < 2; ++t)
        #pragma unroll
        for (int ks = 0; ks < 4; ++ks)
          vr[t * 4 + ks] = *(const uint4*)(Vb + (size_t)(t * 32 + ql) * 2048 + kn + ks * 32 + half * 16);
    }

    // ---- REL band tiles: t2 (cached for kt>0), then t0, then t1; store order t2,t0,t1 ----
    auto relTile = [&](int bt) {
      const int slot = (int)(((unsigned)(rbase >> 6) + (unsigned)((w + bt) >> 1)) % 3u);
      const int rowin = ((w + bt) & 1) * 32 + ql;
      const int tbsw = slot * 8192 + rowin * 128 + ((ql & 7) << 4);
      f32x16 racc = {};
      __builtin_amdgcn_s_setprio(1);
      #pragma unroll
      for (int ds = 0; ds < 4; ++ds) {
        const int cb = ds * 32 + half * 16;
        uint4 tf = *(const uint4*)(Tlds + (tbsw ^ cb));
        racc = __builtin_amdgcn_mfma_f32_32x32x16_bf16(u4_to_s8(tf), qv[ds], racc, 0, 0, 0);
      }
      __builtin_amdgcn_s_setprio(0);
      return racc;
    };

    f32x16 racc2 = (kt == 0) ? relTile(2) : rcache;
    #pragma unroll
    for (int g = 0; g < 4; ++g)
      #pragma unroll
      for (int j = 0; j < 4; ++j) {
        const int pos4 = (u4 + 4 * (-1 - j - 8 * g)) & 124;
        *(float*)(relw + (relsw ^ pos4)) = racc2[4 * g + j];
      }
    f32x16 racc0 = relTile(0);
    #pragma unroll
    for (int g = 0; g < 4; ++g)
      #pragma unroll
      for (int j = 0; j < 4; ++j) {
        const int pos4 = ((u4 + 4 * (63 - j - 8 * g)) & 252) | 128;
        *(float*)(relw + (relsw ^ pos4)) = racc0[4 * g + j];
      }
    rcache = racc0;
    f32x16 racc1 = relTile(1);
    #pragma unroll
    for (int g = 0; g < 4; ++g)
      #pragma unroll
      for (int j = 0; j < 4; ++j) {
        const int pos4 = (u4 + 4 * (31 - j - 8 * g)) & 252;
        *(float*)(relw + (relsw ^ pos4)) = racc1[4 * g + j];
      }

    // ---- QK^T in log2 domain (independent of rel; overlaps the LDS write->read latency) ----
    f32x16 p0 = {}, p1 = {};
    __builtin_amdgcn_s_setprio(1);
    #pragma unroll
    for (int ds = 0; ds < 4; ++ds) {
      const int cb = ds * 32 + half * 16;
      uint4 kf0 = *(const uint4*)(Klds + (k0sw ^ cb));
      uint4 kf1 = *(const uint4*)(Klds + (k1sw ^ cb));
      p0 = __builtin_amdgcn_mfma_f32_32x32x16_bf16(u4_to_s8(kf0), qv[ds], p0, 0, 0, 0);
      p1 = __builtin_amdgcn_mfma_f32_32x32x16_bf16(u4_to_s8(kf1), qv[ds], p1, 0, 0, 0);
    }
    __builtin_amdgcn_s_setprio(0);

    // ---- gather rel quads (vectorized) + add to scores ----
    #pragma unroll
    for (int mp = 0; mp < 4; ++mp) {
      const int X0 = 32 * mp + 16 * half;
      f32x4 r0 = *(const f32x4*)(relw + (relsw ^ X0));
      f32x4 r1 = *(const f32x4*)(relw + (relsw ^ (X0 + 128)));
      #pragma unroll
      for (int j = 0; j < 4; ++j) {
        p0[4 * mp + j] += r0[j];
        p1[4 * mp + j] += r1[j];
      }
    }

    // ---- online softmax (log2 domain, defer-max, tree reductions) ----
    float mx[8];
    #pragma unroll
    for (int i = 0; i < 8; ++i)
      mx[i] = fmaxf(fmaxf(p0[2 * i], p0[2 * i + 1]), fmaxf(p1[2 * i], p1[2 * i + 1]));
    float pmax = fmaxf(fmaxf(fmaxf(mx[0], mx[1]), fmaxf(mx[2], mx[3])),
                       fmaxf(fmaxf(mx[4], mx[5]), fmaxf(mx[6], mx[7])));
    pmax = fmaxf(pmax, __shfl_xor(pmax, 32));
    if (!__all(pmax - mL <= 12.0f)) {
      const float mnew = fmaxf(mL, pmax);
      const float corr = exp2_fast(mL - mnew);
      mL = mnew;
      lsum *= corr;
      #pragma unroll
      for (int r = 0; r < 16; ++r) {
        const float cr = __shfl(corr, (r & 3) + 8 * (r >> 2) + 4 * half);
        cacc0[r] *= cr;
        cacc1[r] *= cr;
      }
    }
    #pragma unroll
    for (int r = 0; r < 16; ++r) {
      p0[r] = exp2_fast(p0[r] - mL);
      p1[r] = exp2_fast(p1[r] - mL);
    }
    float sm[8];
    #pragma unroll
    for (int i = 0; i < 8; ++i)
      sm[i] = (p0[2 * i] + p0[2 * i + 1]) + (p1[2 * i] + p1[2 * i + 1]);
    float psum = ((sm[0] + sm[1]) + (sm[2] + sm[3])) + ((sm[4] + sm[5]) + (sm[6] + sm[7]));
    psum += __shfl_xor(psum, 32);
    lsum += psum;

    // ---- pack P to bf16 words, exchange halves to build PV A-fragments ----
    unsigned int w0[8], w1[8];
    #pragma unroll
    for (int jw = 0; jw < 8; ++jw) {
      w0[jw] = cvtpk(p0[2 * jw], p0[2 * jw + 1]);
      w1[jw] = cvtpk(p1[2 * jw], p1[2 * jw + 1]);
    }
    unsigned int r0x[4], r1x[4];
    #pragma unroll
    for (int i = 0; i < 4; ++i) {
      const int jkeep = (i & 1) + 4 * (i >> 1);      // {0,1,4,5}
      const int jsend = jkeep + 2;                   // {2,3,6,7}
      unsigned int v0 = half ? w0[jkeep] : w0[jsend];
      unsigned int v1 = half ? w1[jkeep] : w1[jsend];
      r0x[i] = (unsigned int)__shfl_xor((int)v0, 32);
      r1x[i] = (unsigned int)__shfl_xor((int)v1, 32);
    }

    // ---- PV: cacc[q][d] += P[q][k] * V[k][d] (V from registers) ----
    __builtin_amdgcn_s_setprio(1);
    #pragma unroll
    for (int ks = 0; ks < 4; ++ks) {
      const int mm = ks & 1;
      unsigned int f0_, f1_, f2_, f3_;
      if (ks < 2) {
        f0_ = half ? r0x[2 * mm]     : w0[4 * mm];
        f1_ = half ? r0x[2 * mm + 1] : w0[4 * mm + 1];
        f2_ = half ? w0[4 * mm + 2]  : r0x[2 * mm];
        f3_ = half ? w0[4 * mm + 3]  : r0x[2 * mm + 1];
      } else {
        f0_ = half ? r1x[2 * mm]     : w1[4 * mm];
        f1_ = half ? r1x[2 * mm + 1] : w1[4 * mm + 1];
        f2_ = half ? w1[4 * mm + 2]  : r1x[2 * mm];
        f3_ = half ? w1[4 * mm + 3]  : r1x[2 * mm + 1];
      }
      s8v pf = words_to_s8(f0_, f1_, f2_, f3_);
      cacc0 = __builtin_amdgcn_mfma_f32_32x32x16_bf16(pf, u4_to_s8(vr[ks]), cacc0, 0, 0, 0);
      cacc1 = __builtin_amdgcn_mfma_f32_32x32x16_bf16(pf, u4_to_s8(vr[4 + ks]), cacc1, 0, 0, 0);
    }
    __builtin_amdgcn_s_setprio(0);
  }

  // ---- epilogue: divide by row sum, store ctx bf16 (coalesced along d=lane) ----
  #pragma unroll
  for (int r = 0; r < 16; ++r) {
    const int qr = (r & 3) + 8 * (r >> 2) + 4 * half;
    const float inv = 1.0f / __shfl(lsum, qr);
    const size_t row = (size_t)b * 1024 + q0 + qr;
    const size_t basei = row * 1024 + h * 64 + ql;
    Cg[basei]      = __float2bfloat16(cacc0[r] * inv);
    Cg[basei + 32] = __float2bfloat16(cacc1[r] * inv);
  }
}

// ---------- launcher ----------
extern "C" void kernel_launch(void* const* d_in, const int* in_sizes, int n_in,
                              void* d_out, int out_size, void* d_ws, size_t ws_size,
                              hipStream_t stream) {
  (void)in_sizes; (void)n_in; (void)out_size; (void)ws_size;
  const float* x  = (const float*)d_in[0];
  const float* wq = (const float*)d_in[1];
  const float* bq = (const float*)d_in[2];
  const float* wk = (const float*)d_in[3];
  const float* bk = (const float*)d_in[4];
  const float* wv = (const float*)d_in[5];
  const float* bv = (const float*)d_in[6];
  const float* wo = (const float*)d_in[7];
  const float* bo = (const float*)d_in[8];
  const float* tb = (const float*)d_in[9];

  char* ws = (char*)d_ws;
  __hip_bfloat16* XB   = (__hip_bfloat16*)(ws);              // [4096][1024]
  __hip_bfloat16* WQKV = (__hip_bfloat16*)(ws + 8388608);    // [3072][1024] (wq|wk|wv)
  __hip_bfloat16* WOb  = (__hip_bfloat16*)(ws + 14680064);   // [1024][1024]
  __hip_bfloat16* TBL  = (__hip_bfloat16*)(ws + 16777216);   // [16][2048][64]
  __hip_bfloat16* QB   = (__hip_bfloat16*)(ws + 20971520);   // [4][16][1024][64]
  __hip_bfloat16* KB   = (__hip_bfloat16*)(ws + 29360128);   // [4][16][1024][64]
  __hip_bfloat16* VTB  = (__hip_bfloat16*)(ws + 37748736);   // [4][16][64][1024]
  __hip_bfloat16* CTX  = (__hip_bfloat16*)(ws + 46137344);   // [4096][1024]

  cvt_xw_kernel<<<4096, 256, 0, stream>>>(x, wq, wk, wv, wo, XB, WQKV, WOb);
  gemm_qkv<<<1792, 256, 0, stream>>>(XB, WQKV, bq, bk, bv, QB, KB, VTB, tb, TBL);
  attn_kernel<<<512, 256, 0, stream>>>(QB, KB, VTB, TBL, CTX);
  gemm_out<<<512, 256, 0, stream>>>(CTX, WOb, bo, (float*)d_out);
}

// Round 13
// 103.478 us; speedup vs baseline: 1.6346x; 1.0148x over previous
//
#include <hip/hip_runtime.h>
#include <hip/hip_bf16.h>
#include <stdint.h>

// ---------- types / helpers ----------
typedef __attribute__((ext_vector_type(8))) short s8v;      // 8 x bf16 (4 VGPR)
typedef __attribute__((ext_vector_type(4))) float f32x4;
typedef __attribute__((ext_vector_type(16))) float f32x16;

union V16 { uint4 u4; unsigned int u[4]; s8v s; };

__device__ inline s8v u4_to_s8(uint4 v) { V16 c; c.u4 = v; return c.s; }
__device__ inline s8v words_to_s8(unsigned int a, unsigned int b, unsigned int c, unsigned int d) {
  V16 t; t.u[0] = a; t.u[1] = b; t.u[2] = c; t.u[3] = d; return t.s;
}
__device__ inline unsigned short f2b(float f) {
  __hip_bfloat16 h = __float2bfloat16(f);
  unsigned short u; __builtin_memcpy(&u, &h, 2); return u;
}
__device__ inline unsigned int pack2(float lo, float hi) {
  return ((unsigned int)f2b(hi) << 16) | (unsigned int)f2b(lo);
}
// packed f32->bf16 pair (RNE), 1 instruction
__device__ inline unsigned int cvtpk(float lo, float hi) {
  unsigned int r; asm("v_cvt_pk_bf16_f32 %0, %1, %2" : "=v"(r) : "v"(lo), "v"(hi)); return r;
}
__device__ inline float exp2_fast(float x) {
#if __has_builtin(__builtin_amdgcn_exp2f)
  return __builtin_amdgcn_exp2f(x);
#else
  float y; asm("v_exp_f32 %0, %1" : "=v"(y) : "v"(x)); return y;
#endif
}
// async global->LDS, 16B per lane; LDS dest = wave-uniform base + lane*16
__device__ inline void gld16(const void* g, void* lds) {
  __builtin_amdgcn_global_load_lds((const __attribute__((address_space(1))) void*)g,
                                   (__attribute__((address_space(3))) void*)lds, 16, 0, 0);
}

#define LOG2E 1.4426950408889634f

// ---------- convert kernel: x, wq, wk, wv, wo only (table rides in gemm_qkv grid) ----------
__global__ void cvt_xw_kernel(const float* __restrict__ x, const float* __restrict__ wq,
                              const float* __restrict__ wk, const float* __restrict__ wv,
                              const float* __restrict__ wo,
                              __hip_bfloat16* __restrict__ XB, __hip_bfloat16* __restrict__ WQKV,
                              __hip_bfloat16* __restrict__ WOb) {
  size_t i = ((size_t)blockIdx.x * 256 + threadIdx.x) * 8;
  const float* src; __hip_bfloat16* dst; size_t off;
  if (i < 4194304)      { src = x;  dst = XB;             off = i; }
  else if (i < 5242880) { src = wq; dst = WQKV;           off = i - 4194304; }
  else if (i < 6291456) { src = wk; dst = WQKV + 1048576; off = i - 5242880; }
  else if (i < 7340032) { src = wv; dst = WQKV + 2097152; off = i - 6291456; }
  else                  { src = wo; dst = WOb;            off = i - 7340032; }
  const float4* s4 = (const float4*)(src + off);
  float4 a = s4[0], b = s4[1];
  uint4 o;
  o.x = pack2(a.x, a.y); o.y = pack2(a.z, a.w);
  o.z = pack2(b.x, b.y); o.w = pack2(b.z, b.w);
  *(uint4*)(dst + off) = o;
}

// ---------- QKV GEMM + fused table convert ----------
// flat grid 1792: blocks 0..767 = GEMM (XCD-swizzled: wg=(g%8)*96+g/8), n-tile = wg%24
// [0-7 Q, 8-15 K, 16-23 V], m-tile = wg/24; blocks 768..1791 = rpe_table -> TBL bf16.
__global__ __launch_bounds__(256, 3) void gemm_qkv(
    const __hip_bfloat16* __restrict__ A,      // XB [4096][1024]
    const __hip_bfloat16* __restrict__ Bt,     // WQKV [3072][1024]
    const float* __restrict__ bq, const float* __restrict__ bk, const float* __restrict__ bv,
    __hip_bfloat16* __restrict__ QB, __hip_bfloat16* __restrict__ KB,
    __hip_bfloat16* __restrict__ VTB,
    const float* __restrict__ tb, __hip_bfloat16* __restrict__ TBL) {
  const int flat = blockIdx.x;
  if (flat >= 768) {
    size_t i = ((size_t)(flat - 768) * 256 + threadIdx.x) * 8;
    int h = (int)(i >> 17);
    int rem = (int)(i & 131071);
    int r = rem >> 6, c = rem & 63;
    uint4 o;
    if (r < 2047) {
      const float4* s4 = (const float4*)(tb + ((size_t)h * 9999 + r) * 64 + c);
      float4 a = s4[0], b = s4[1];
      o.x = pack2(a.x * LOG2E, a.y * LOG2E); o.y = pack2(a.z * LOG2E, a.w * LOG2E);
      o.z = pack2(b.x * LOG2E, b.y * LOG2E); o.w = pack2(b.z * LOG2E, b.w * LOG2E);
    } else { o.x = 0u; o.y = 0u; o.z = 0u; o.w = 0u; }
    *(uint4*)(TBL + i) = o;
    return;
  }

  __shared__ __align__(16) char smem[32768];
  char* As = smem;
  char* Bs = smem + 16384;
  const int tid = threadIdx.x;
  const int w = tid >> 6, l = tid & 63;
  const int wr = w >> 1, wc = w & 1;
  const int lr = l & 15, lg = l >> 4;
  const int wg = (flat & 7) * 96 + (flat >> 3);   // bijective XCD swizzle (768 % 8 == 0)
  const int nt = wg % 24, mt = wg / 24;
  const int m0 = mt * 128, n0 = nt * 128;

  f32x4 acc[4][4] = {};

  for (int kt = 0; kt < 16; ++kt) {
    __syncthreads();
    #pragma unroll
    for (int i = 0; i < 4; ++i) {
      const int off = i * 4096 + w * 1024;
      const int loff = off + l * 16;
      const int row = loff >> 7;
      const int cb = loff & 127;
      const int sc = cb ^ ((row & 7) << 4);
      gld16((const char*)A  + (size_t)(m0 + row) * 2048 + kt * 128 + sc, As + off);
      gld16((const char*)Bt + (size_t)(n0 + row) * 2048 + kt * 128 + sc, Bs + off);
    }
    asm volatile("s_waitcnt vmcnt(0)" ::: "memory");
    __syncthreads();
    #pragma unroll
    for (int ks = 0; ks < 2; ++ks) {
      uint4 af[4], bf4[4];
      #pragma unroll
      for (int i = 0; i < 4; ++i) {
        const int ra = wr * 64 + i * 16 + lr;
        const int rb = wc * 64 + i * 16 + lr;
        const int cb = ks * 64 + lg * 16;
        af[i]  = *(const uint4*)(As + ra * 128 + (cb ^ ((ra & 7) << 4)));
        bf4[i] = *(const uint4*)(Bs + rb * 128 + (cb ^ ((rb & 7) << 4)));
      }
      #pragma unroll
      for (int i = 0; i < 4; ++i) {
        #pragma unroll
        for (int j = 0; j < 4; ++j)
          acc[i][j] = __builtin_amdgcn_mfma_f32_16x16x32_bf16(u4_to_s8(af[i]), u4_to_s8(bf4[j]), acc[i][j], 0, 0, 0);
      }
    }
  }

  const int mrow = m0 + wr * 64 + lg * 4;
  const int ncol = n0 + wc * 64 + lr;
  const int cls = nt >> 3;            // 0 = Q, 1 = K, 2 = V (block-uniform)

  if (cls < 2) {
    const float sc = cls ? 0.125f * LOG2E : 1.0f;
    const float* bias = cls ? bk : bq;
    __hip_bfloat16* op = cls ? KB : QB;
    #pragma unroll
    for (int j = 0; j < 4; ++j) {
      const int n = ncol - cls * 1024 + j * 16;
      const float bia = bias[n];
      const int hh = n >> 6, hd = n & 63;
      #pragma unroll
      for (int i = 0; i < 4; ++i) {
        #pragma unroll
        for (int r = 0; r < 4; ++r) {
          const int m = mrow + i * 16 + r;
          const int bb = m >> 10, ss = m & 1023;
          op[(((size_t)(bb * 16 + hh)) * 1024 + ss) * 64 + hd] = __float2bfloat16((acc[i][j][r] + bia) * sc);
        }
      }
    }
  } else {
    // V: write VT [B][H][64][S]; quad of consecutive s -> one 8B store
    #pragma unroll
    for (int j = 0; j < 4; ++j) {
      const int f = ncol - 2048 + j * 16;      // v feature = h*64+hd
      const float bia = bv[f];
      const int fh = f >> 6, fd = f & 63;
      #pragma unroll
      for (int i = 0; i < 4; ++i) {
        const int m = mrow + i * 16;          // quad m..m+3, m%4==0
        const int bb = m >> 10, ss = m & 1023;
        ushort4 qv;
        qv.x = f2b(acc[i][j][0] + bia); qv.y = f2b(acc[i][j][1] + bia);
        qv.z = f2b(acc[i][j][2] + bia); qv.w = f2b(acc[i][j][3] + bia);
        *(ushort4*)((char*)VTB + (((size_t)bb * 1048576 + (size_t)fh * 65536 + fd * 1024 + ss) * 2)) = qv;
      }
    }
  }
}

// ---------- out-proj GEMM: d_out[m][n] = CTX[m]·WOb[n] + bo, f32 out ----------
// 64x64 tile: grid 1024 (XCD-swizzled), launch_bounds(256,4) -> 4 blocks/CU = 16 waves/CU
// (r12 was 512 blocks = 2/CU = 8 waves). 4 waves as 2x2, each 32x32 out (acc[2][2]); LDS 16K.
__global__ __launch_bounds__(256, 4) void gemm_out(
    const __hip_bfloat16* __restrict__ A,      // CTX [4096][1024]
    const __hip_bfloat16* __restrict__ Bt,     // WOb [1024][1024]
    const float* __restrict__ bo,
    float* __restrict__ out) {
  __shared__ __align__(16) char smem[16384];
  char* As = smem;
  char* Bs = smem + 8192;
  const int tid = threadIdx.x;
  const int w = tid >> 6, l = tid & 63;
  const int wr = w >> 1, wc = w & 1;
  const int lr = l & 15, lg = l >> 4;
  const int flat = blockIdx.x;
  const int wg = (flat & 7) * 128 + (flat >> 3);  // bijective XCD swizzle (1024 % 8 == 0)
  const int nt = wg & 15, mt = wg >> 4;           // 64 m-tiles x 16 n-tiles
  const int m0 = mt * 64, n0 = nt * 64;

  f32x4 acc[2][2] = {};

  for (int kt = 0; kt < 16; ++kt) {
    __syncthreads();
    #pragma unroll
    for (int i = 0; i < 2; ++i) {
      const int off = i * 4096 + w * 1024;
      const int loff = off + l * 16;
      const int row = loff >> 7;
      const int cb = loff & 127;
      const int sc = cb ^ ((row & 7) << 4);
      gld16((const char*)A  + (size_t)(m0 + row) * 2048 + kt * 128 + sc, As + off);
      gld16((const char*)Bt + (size_t)(n0 + row) * 2048 + kt * 128 + sc, Bs + off);
    }
    asm volatile("s_waitcnt vmcnt(0)" ::: "memory");
    __syncthreads();
    #pragma unroll
    for (int ks = 0; ks < 2; ++ks) {
      uint4 af[2], bf2[2];
      #pragma unroll
      for (int i = 0; i < 2; ++i) {
        const int ra = wr * 32 + i * 16 + lr;
        const int cb = ks * 64 + lg * 16;
        af[i] = *(const uint4*)(As + ra * 128 + (cb ^ ((ra & 7) << 4)));
      }
      #pragma unroll
      for (int j = 0; j < 2; ++j) {
        const int rb = wc * 32 + j * 16 + lr;
        const int cb = ks * 64 + lg * 16;
        bf2[j] = *(const uint4*)(Bs + rb * 128 + (cb ^ ((rb & 7) << 4)));
      }
      #pragma unroll
      for (int i = 0; i < 2; ++i) {
        #pragma unroll
        for (int j = 0; j < 2; ++j)
          acc[i][j] = __builtin_amdgcn_mfma_f32_16x16x32_bf16(u4_to_s8(af[i]), u4_to_s8(bf2[j]), acc[i][j], 0, 0, 0);
      }
    }
  }

  const int mrow = m0 + wr * 32 + lg * 4;
  const int ncol = n0 + wc * 32 + lr;
  #pragma unroll
  for (int j = 0; j < 2; ++j) {
    const int n = ncol + j * 16;
    const float bia = bo[n];
    #pragma unroll
    for (int i = 0; i < 2; ++i) {
      #pragma unroll
      for (int r = 0; r < 4; ++r) {
        const int m = mrow + i * 16 + r;
        out[(size_t)m * 1024 + n] = acc[i][j][r] + bia;
      }
    }
  }
}

// ---------- fused attention with RPE (v13: r6 skeleton, kt unrolled x2 per superstep) ----------
// grid 512 (XCD-chunk swizzled), 256 threads = 4 waves, 32 q-rows/wave -- SAME wave structure
// and compute bodies as r6 (proven); only the staging cadence changes: one stage+drain+barrier
// pair per 2 kt (16 bar + 8 drains vs r6's 32 + 16).
// LDS 80 KB = K dbuf 2x8K (buf = kt&1) + T ring-4 32K (slot = chunk&3) + rel f32 4x8K
// -> 2 blocks/CU (80*2 = 160K exactly).
// Window invariant (single sequential group -- no cross-group sharing): superstep s uses
// chunks [c_s-1, c_s+2] where c_s = (qb+960-128s)>>6; at boundary stage c_{s+1}-1, c_{s+1}
// (= c_s-3, c_s-2) into slots of retired c_s+1, c_s+2; retained c_s-1, c_s serve s+1.
// Hand-simulated for qt=0: prologue {14,15,16,17}; s-boundary stages {12-2s, 13-2s}; holds.
__global__ __launch_bounds__(256, 2) void attn_kernel(
    const __hip_bfloat16* __restrict__ Qg,   // [B][H][S][64]
    const __hip_bfloat16* __restrict__ Kg,   // [B][H][S][64] (pre-scaled 0.125*log2e)
    const __hip_bfloat16* __restrict__ VTg,  // [B][H][64][S]
    const __hip_bfloat16* __restrict__ Tg,   // [H][2048][64] (pre-scaled log2e)
    __hip_bfloat16* __restrict__ Cg) {       // [B*S][1024]
  __shared__ __align__(16) char smem[81920];
  char* Klds = smem;                  // 2 x 8 KB dbuf (buf = kt & 1)
  char* Tlds = smem + 16384;          // 4 x 8 KB ring (slot = chunk & 3)
  const int tid = threadIdx.x;
  const int w = tid >> 6, l = tid & 63;
  const int ql = l & 31, half = l >> 5;
  char* relw = smem + 49152 + w * 8192;  // per-wave [32 q][64 kl] f32, 16B-granule XOR swizzle

  const int bx = blockIdx.x;
  const int work = (bx & 7) * 64 + (bx >> 3);   // XCD-chunk swizzle
  const int b = work & 3, hqt = work >> 2;
  const int h = hqt >> 3, qt = hqt & 7;
  const int qb = qt * 128;
  const int q0 = qb + 32 * w;

  const size_t bh = (size_t)(b * 16 + h);
  const char* Qb = (const char*)Qg + bh * 131072;
  const char* Kb = (const char*)Kg + bh * 131072;
  const char* Vb = (const char*)VTg + bh * 131072;
  const char* Tb = (const char*)Tg + (size_t)h * 262144;

  // per-lane precomputed addressing
  const int relsw = ql * 256 + ((ql & 15) << 4);          // rel row base | swizzle
  const int u4 = (ql << 2) - (half << 4);                 // 4*(ql - 4*half)
  const int k0sw = ql * 128 + ((ql & 7) << 4);            // K row ql, swizzled
  const int k1sw = (32 + ql) * 128 + ((ql & 7) << 4);     // K row 32+ql

  auto stageK = [&](int k0n, int buf) {
    #pragma unroll
    for (int i = 0; i < 2; ++i) {
      const int loff = i * 4096 + w * 1024 + l * 16;
      const int row = loff >> 7, cb = loff & 127;
      const int sc = cb ^ ((row & 7) << 4);
      gld16(Kb + (size_t)(k0n + row) * 128 + sc, Klds + buf * 8192 + i * 4096 + w * 1024);
    }
  };
  auto stageT = [&](int c) {           // chunk index (absolute row>>6), slot = c&3
    char* dst = Tlds + (c & 3) * 8192;
    #pragma unroll
    for (int i = 0; i < 2; ++i) {
      const int loff = i * 4096 + w * 1024 + l * 16;
      const int row = loff >> 7, cb = loff & 127;
      const int sc = cb ^ ((row & 7) << 4);
      gld16(Tb + ((size_t)c * 64 + row) * 128 + sc, dst + i * 4096 + w * 1024);
    }
  };

  // Q fragments (B-operand: lane holds Q[q0+ql][16*ds + 8*half + t])
  s8v qv[4];
  {
    const char* qrow = Qb + (size_t)(q0 + ql) * 128 + half * 16;
    #pragma unroll
    for (int ds = 0; ds < 4; ++ds) qv[ds] = u4_to_s8(*(const uint4*)(qrow + ds * 32));
  }

  f32x16 cacc0 = {}, cacc1 = {};        // ctx[q over regs][d = tile*32 + lane]
  f32x16 rcache = {};                   // REL tile (w,0) of previous kt == (w,2) of this kt
  float mL = -1.0e30f, lsum = 0.0f;     // log2-domain running max / prob sum

  // r6-verbatim compute body for one kt (kbase selects K dbuf half)
  auto computeKT = [&](int kt, int kbase) {
    const int rbase = qb + 960 - 64 * kt;

    // ---- V(kt) -> registers (plain loads; compiler places the waitcnt before PV) ----
    uint4 vr[8];
    { const int kn = kt * 128;
      #pragma unroll
      for (int t = 0; t < 2; ++t)
        #pragma unroll
        for (int ks = 0; ks < 4; ++ks)
          vr[t * 4 + ks] = *(const uint4*)(Vb + (size_t)(t * 32 + ql) * 2048 + kn + ks * 32 + half * 16);
    }

    // ---- REL band tiles: t2 (cached for kt>0), then t0, then t1; store order t2,t0,t1 ----
    auto relTile = [&](int bt) {
      const int slot = ((rbase >> 6) + ((w + bt) >> 1)) & 3;
      const int rowin = ((w + bt) & 1) * 32 + ql;
      const int tbsw = slot * 8192 + rowin * 128 + ((ql & 7) << 4);
      f32x16 racc = {};
      __builtin_amdgcn_s_setprio(1);
      #pragma unroll
      for (int ds = 0; ds < 4; ++ds) {
        const int cb = ds * 32 + half * 16;
        uint4 tf = *(const uint4*)(Tlds + (tbsw ^ cb));
        racc = __builtin_amdgcn_mfma_f32_32x32x16_bf16(u4_to_s8(tf), qv[ds], racc, 0, 0, 0);
      }
      __builtin_amdgcn_s_setprio(0);
      return racc;
    };

    f32x16 racc2 = (kt == 0) ? relTile(2) : rcache;
    #pragma unroll
    for (int g = 0; g < 4; ++g)
      #pragma unroll
      for (int j = 0; j < 4; ++j) {
        const int pos4 = (u4 + 4 * (-1 - j - 8 * g)) & 124;
        *(float*)(relw + (relsw ^ pos4)) = racc2[4 * g + j];
      }
    f32x16 racc0 = relTile(0);
    #pragma unroll
    for (int g = 0; g < 4; ++g)
      #pragma unroll
      for (int j = 0; j < 4; ++j) {
        const int pos4 = ((u4 + 4 * (63 - j - 8 * g)) & 252) | 128;
        *(float*)(relw + (relsw ^ pos4)) = racc0[4 * g + j];
      }
    rcache = racc0;
    f32x16 racc1 = relTile(1);
    #pragma unroll
    for (int g = 0; g < 4; ++g)
      #pragma unroll
      for (int j = 0; j < 4; ++j) {
        const int pos4 = (u4 + 4 * (31 - j - 8 * g)) & 252;
        *(float*)(relw + (relsw ^ pos4)) = racc1[4 * g + j];
      }

    // ---- QK^T in log2 domain (overlaps the rel LDS write->read latency) ----
    f32x16 p0 = {}, p1 = {};
    __builtin_amdgcn_s_setprio(1);
    #pragma unroll
    for (int ds = 0; ds < 4; ++ds) {
      const int cb = ds * 32 + half * 16;
      uint4 kf0 = *(const uint4*)(Klds + kbase + (k0sw ^ cb));
      uint4 kf1 = *(const uint4*)(Klds + kbase + (k1sw ^ cb));
      p0 = __builtin_amdgcn_mfma_f32_32x32x16_bf16(u4_to_s8(kf0), qv[ds], p0, 0, 0, 0);
      p1 = __builtin_amdgcn_mfma_f32_32x32x16_bf16(u4_to_s8(kf1), qv[ds], p1, 0, 0, 0);
    }
    __builtin_amdgcn_s_setprio(0);

    // ---- gather rel quads (vectorized) + add to scores ----
    #pragma unroll
    for (int mp = 0; mp < 4; ++mp) {
      const int X0 = 32 * mp + 16 * half;
      f32x4 r0 = *(const f32x4*)(relw + (relsw ^ X0));
      f32x4 r1 = *(const f32x4*)(relw + (relsw ^ (X0 + 128)));
      #pragma unroll
      for (int j = 0; j < 4; ++j) {
        p0[4 * mp + j] += r0[j];
        p1[4 * mp + j] += r1[j];
      }
    }

    // ---- online softmax (log2 domain, defer-max, tree reductions) ----
    float mx[8];
    #pragma unroll
    for (int i = 0; i < 8; ++i)
      mx[i] = fmaxf(fmaxf(p0[2 * i], p0[2 * i + 1]), fmaxf(p1[2 * i], p1[2 * i + 1]));
    float pmax = fmaxf(fmaxf(fmaxf(mx[0], mx[1]), fmaxf(mx[2], mx[3])),
                       fmaxf(fmaxf(mx[4], mx[5]), fmaxf(mx[6], mx[7])));
    pmax = fmaxf(pmax, __shfl_xor(pmax, 32));
    if (!__all(pmax - mL <= 12.0f)) {
      const float mnew = fmaxf(mL, pmax);
      const float corr = exp2_fast(mL - mnew);
      mL = mnew;
      lsum *= corr;
      #pragma unroll
      for (int r = 0; r < 16; ++r) {
        const float cr = __shfl(corr, (r & 3) + 8 * (r >> 2) + 4 * half);
        cacc0[r] *= cr;
        cacc1[r] *= cr;
      }
    }
    #pragma unroll
    for (int r = 0; r < 16; ++r) {
      p0[r] = exp2_fast(p0[r] - mL);
      p1[r] = exp2_fast(p1[r] - mL);
    }
    float sm[8];
    #pragma unroll
    for (int i = 0; i < 8; ++i)
      sm[i] = (p0[2 * i] + p0[2 * i + 1]) + (p1[2 * i] + p1[2 * i + 1]);
    float psum = ((sm[0] + sm[1]) + (sm[2] + sm[3])) + ((sm[4] + sm[5]) + (sm[6] + sm[7]));
    psum += __shfl_xor(psum, 32);
    lsum += psum;

    // ---- pack P to bf16 words, exchange halves to build PV A-fragments ----
    unsigned int w0[8], w1[8];
    #pragma unroll
    for (int jw = 0; jw < 8; ++jw) {
      w0[jw] = cvtpk(p0[2 * jw], p0[2 * jw + 1]);
      w1[jw] = cvtpk(p1[2 * jw], p1[2 * jw + 1]);
    }
    unsigned int r0x[4], r1x[4];
    #pragma unroll
    for (int i = 0; i < 4; ++i) {
      const int jkeep = (i & 1) + 4 * (i >> 1);      // {0,1,4,5}
      const int jsend = jkeep + 2;                   // {2,3,6,7}
      unsigned int v0 = half ? w0[jkeep] : w0[jsend];
      unsigned int v1 = half ? w1[jkeep] : w1[jsend];
      r0x[i] = (unsigned int)__shfl_xor((int)v0, 32);
      r1x[i] = (unsigned int)__shfl_xor((int)v1, 32);
    }

    // ---- PV: cacc[q][d] += P[q][k] * V[k][d] (V from registers) ----
    __builtin_amdgcn_s_setprio(1);
    #pragma unroll
    for (int ks = 0; ks < 4; ++ks) {
      const int mm = ks & 1;
      unsigned int f0_, f1_, f2_, f3_;
      if (ks < 2) {
        f0_ = half ? r0x[2 * mm]     : w0[4 * mm];
        f1_ = half ? r0x[2 * mm + 1] : w0[4 * mm + 1];
        f2_ = half ? w0[4 * mm + 2]  : r0x[2 * mm];
        f3_ = half ? w0[4 * mm + 3]  : r0x[2 * mm + 1];
      } else {
        f0_ = half ? r1x[2 * mm]     : w1[4 * mm];
        f1_ = half ? r1x[2 * mm + 1] : w1[4 * mm + 1];
        f2_ = half ? w1[4 * mm + 2]  : r1x[2 * mm];
        f3_ = half ? w1[4 * mm + 3]  : r1x[2 * mm + 1];
      }
      s8v pf = words_to_s8(f0_, f1_, f2_, f3_);
      cacc0 = __builtin_amdgcn_mfma_f32_32x32x16_bf16(pf, u4_to_s8(vr[ks]), cacc0, 0, 0, 0);
      cacc1 = __builtin_amdgcn_mfma_f32_32x32x16_bf16(pf, u4_to_s8(vr[4 + ks]), cacc1, 0, 0, 0);
    }
    __builtin_amdgcn_s_setprio(0);
  };

  // ---- prologue: K(0)->buf0, K(1)->buf1, T chunks c0-1..c0+2; drain + barrier ----
  const int c0 = (qb + 960) >> 6;
  stageK(0, 0); stageK(64, 1);
  stageT(c0 - 1); stageT(c0); stageT(c0 + 1); stageT(c0 + 2);
  asm volatile("s_waitcnt vmcnt(0)" ::: "memory");
  __syncthreads();

  for (int s = 0; s < 8; ++s) {
    computeKT(2 * s, 0);
    computeKT(2 * s + 1, 8192);
    __syncthreads();                     // all reads of this superstep's K/T done
    if (s < 7) {
      stageK((2 * s + 2) * 64, 0);
      stageK((2 * s + 3) * 64, 1);
      const int cn = (qb + 960 - 128 * (s + 1)) >> 6;
      stageT(cn - 1); stageT(cn);        // into slots of retired c_s+1, c_s+2
      asm volatile("s_waitcnt vmcnt(0)" ::: "memory");
    }
    __syncthreads();
  }

  // ---- epilogue: divide by row sum, store ctx bf16 (coalesced along d=lane) ----
  #pragma unroll
  for (int r = 0; r < 16; ++r) {
    const int qr = (r & 3) + 8 * (r >> 2) + 4 * half;
    const float inv = 1.0f / __shfl(lsum, qr);
    const size_t row = (size_t)b * 1024 + q0 + qr;
    const size_t basei = row * 1024 + h * 64 + ql;
    Cg[basei]      = __float2bfloat16(cacc0[r] * inv);
    Cg[basei + 32] = __float2bfloat16(cacc1[r] * inv);
  }
}

// ---------- launcher ----------
extern "C" void kernel_launch(void* const* d_in, const int* in_sizes, int n_in,
                              void* d_out, int out_size, void* d_ws, size_t ws_size,
                              hipStream_t stream) {
  (void)in_sizes; (void)n_in; (void)out_size; (void)ws_size;
  const float* x  = (const float*)d_in[0];
  const float* wq = (const float*)d_in[1];
  const float* bq = (const float*)d_in[2];
  const float* wk = (const float*)d_in[3];
  const float* bk = (const float*)d_in[4];
  const float* wv = (const float*)d_in[5];
  const float* bv = (const float*)d_in[6];
  const float* wo = (const float*)d_in[7];
  const float* bo = (const float*)d_in[8];
  const float* tb = (const float*)d_in[9];

  char* ws = (char*)d_ws;
  __hip_bfloat16* XB   = (__hip_bfloat16*)(ws);              // [4096][1024]
  __hip_bfloat16* WQKV = (__hip_bfloat16*)(ws + 8388608);    // [3072][1024] (wq|wk|wv)
  __hip_bfloat16* WOb  = (__hip_bfloat16*)(ws + 14680064);   // [1024][1024]
  __hip_bfloat16* TBL  = (__hip_bfloat16*)(ws + 16777216);   // [16][2048][64]
  __hip_bfloat16* QB   = (__hip_bfloat16*)(ws + 20971520);   // [4][16][1024][64]
  __hip_bfloat16* KB   = (__hip_bfloat16*)(ws + 29360128);   // [4][16][1024][64]
  __hip_bfloat16* VTB  = (__hip_bfloat16*)(ws + 37748736);   // [4][16][64][1024]
  __hip_bfloat16* CTX  = (__hip_bfloat16*)(ws + 46137344);   // [4096][1024]

  cvt_xw_kernel<<<4096, 256, 0, stream>>>(x, wq, wk, wv, wo, XB, WQKV, WOb);
  gemm_qkv<<<1792, 256, 0, stream>>>(XB, WQKV, bq, bk, bv, QB, KB, VTB, tb, TBL);
  attn_kernel<<<512, 256, 0, stream>>>(QB, KB, VTB, TBL, CTX);
  gemm_out<<<1024, 256, 0, stream>>>(CTX, WOb, bo, (float*)d_out);
}